// Round 2
// baseline (2039.595 us; speedup 1.0000x reference)
//
#include <hip/hip_runtime.h>
#include <hip/hip_bf16.h>
#include <math.h>

// Problem constants
constexpr int Bc = 4, Sc = 16, Pc = 256, Ec = 768, Hc = 12, HDc = 64, FFc = 3072;
constexpr int Mrows = Bc * Sc * Pc;              // 16384 token rows
constexpr size_t ME = (size_t)Mrows * Ec;        // 12,582,912 elements

typedef __attribute__((ext_vector_type(4))) float f32x4;
typedef __attribute__((ext_vector_type(8))) short s16x8;
typedef __attribute__((ext_vector_type(4))) short s16x4;

__device__ __forceinline__ short f2bf(float f) {
  union { float f; unsigned u; } v; v.f = f;
  unsigned r = (v.u + 0x7FFFu + ((v.u >> 16) & 1u)) >> 16;  // RNE
  return (short)r;
}
__device__ __forceinline__ float bf2f(short s) {
  union { unsigned u; float f; } v; v.u = ((unsigned)(unsigned short)s) << 16;
  return v.f;
}

// ---------------------------------------------------------------------------
// fp32 -> bf16 convert (vectorized, 8 elems/thread)
// ---------------------------------------------------------------------------
__global__ __launch_bounds__(256)
void f2bf_kernel(const float* __restrict__ in, short* __restrict__ out, int n8)
{
  int i = blockIdx.x * 256 + threadIdx.x;
  if (i >= n8) return;
  const float4* p = reinterpret_cast<const float4*>(in + (size_t)i * 8);
  float4 a = p[0], b = p[1];
  s16x8 o = { f2bf(a.x), f2bf(a.y), f2bf(a.z), f2bf(a.w),
              f2bf(b.x), f2bf(b.y), f2bf(b.z), f2bf(b.w) };
  *reinterpret_cast<s16x8*>(out + (size_t)i * 8) = o;
}

// ---------------------------------------------------------------------------
// GEMM: C[z] = A[M,K](bf16) * W[z][K,N](fp32->bf16) + bias[z]
// OUT: 0 = bf16 store, 1 = bf16 store + relu,
//      2 = fp32 store + fp32 residual, 3 = fp32 store + bf16 residual
// 64x64 tile, 4 waves (2x2), BK=32, bf16 MFMA 16x16x32, fp32 accum.
// ---------------------------------------------------------------------------
template<int OUT>
__global__ __launch_bounds__(256)
void gemm_kernel(const short* __restrict__ A, const float* __restrict__ Wg,
                 const float* __restrict__ biasg, const void* __restrict__ resv,
                 void* __restrict__ Cg, int M, int N, int K)
{
  const int z = blockIdx.z;
  const float* W  = Wg    + (size_t)z * K * N;
  const float* bz = biasg + (size_t)z * N;

  const int bm = blockIdx.x * 64;
  const int bn = blockIdx.y * 64;

  // stride 40 shorts = 80B rows (16B-aligned, breaks pow2 banking)
  __shared__ alignas(16) short As[64][40];
  __shared__ alignas(16) short Bs[64][40];   // Bs[n][k] (transposed)

  const int tid  = threadIdx.x;
  const int lane = tid & 63;
  const int wid  = tid >> 6;
  const int wr   = wid >> 1, wc = wid & 1;
  const int l16  = lane & 15;
  const int kb   = (lane >> 4) * 8;

  const f32x4 zero = {0.f, 0.f, 0.f, 0.f};
  f32x4 acc[2][2] = {{zero, zero}, {zero, zero}};

  for (int k0 = 0; k0 < K; k0 += 32) {
    // stage A tile: 64 rows x 32 k, bf16, 256 threads x 16B
    {
      int r = tid >> 2, c8 = (tid & 3) * 8;
      *reinterpret_cast<s16x8*>(&As[r][c8]) =
          *reinterpret_cast<const s16x8*>(&A[(size_t)(bm + r) * K + k0 + c8]);
    }
    // stage B tile transposed: Bs[n][k] = bf16(W[k0+k][bn+n])
#pragma unroll
    for (int it = 0; it < 2; ++it) {
      int i = tid + it * 256;
      int k = i >> 4, c4 = i & 15;
      float4 v = *reinterpret_cast<const float4*>(&W[(size_t)(k0 + k) * N + bn + c4 * 4]);
      Bs[c4 * 4 + 0][k] = f2bf(v.x);
      Bs[c4 * 4 + 1][k] = f2bf(v.y);
      Bs[c4 * 4 + 2][k] = f2bf(v.z);
      Bs[c4 * 4 + 3][k] = f2bf(v.w);
    }
    __syncthreads();

    s16x8 a[2], b[2];
#pragma unroll
    for (int m = 0; m < 2; ++m)
      a[m] = *reinterpret_cast<const s16x8*>(&As[wr * 32 + m * 16 + l16][kb]);
#pragma unroll
    for (int n = 0; n < 2; ++n)
      b[n] = *reinterpret_cast<const s16x8*>(&Bs[wc * 32 + n * 16 + l16][kb]);
#pragma unroll
    for (int m = 0; m < 2; ++m)
#pragma unroll
      for (int n = 0; n < 2; ++n)
        acc[m][n] = __builtin_amdgcn_mfma_f32_16x16x32_bf16(a[m], b[n], acc[m][n], 0, 0, 0);
    __syncthreads();
  }

  const float* resf = (const float*)resv;
  const short* resb = (const short*)resv;
  short* Cb = (short*)Cg + (size_t)z * (size_t)M * N;
  float* Cf = (float*)Cg + (size_t)z * (size_t)M * N;

#pragma unroll
  for (int m = 0; m < 2; ++m)
#pragma unroll
    for (int n = 0; n < 2; ++n) {
      const int row0 = bm + wr * 32 + m * 16 + (lane >> 4) * 4;
      const int col  = bn + wc * 32 + n * 16 + l16;
#pragma unroll
      for (int r = 0; r < 4; ++r) {
        float v = acc[m][n][r] + bz[col];
        size_t idx = (size_t)(row0 + r) * N + col;
        if (OUT == 2) v += resf[idx];
        if (OUT == 3) v += bf2f(resb[idx]);
        if (OUT == 1) v = fmaxf(v, 0.f);
        if (OUT <= 1) Cb[idx] = f2bf(v);
        else          Cf[idx] = v;
      }
    }
}

// ---------------------------------------------------------------------------
// Spatial attention: per (b*S+s, h) block; 256 threads = 256 query rows.
// K and V staged in LDS (bf16, 32KB each); online softmax; O in-place over Q.
// ---------------------------------------------------------------------------
__global__ __launch_bounds__(256)
void spatial_attn_kernel(const short* __restrict__ Qg, const short* __restrict__ Kg,
                         const short* __restrict__ Vg, short* __restrict__ Og)
{
  const int bs = blockIdx.x;   // 0..63 (b*S+s)
  const int h  = blockIdx.y;   // 0..11
  const size_t base = (size_t)bs * Pc * Ec + (size_t)h * HDc;

  __shared__ short Ks[Pc][HDc];   // 32 KB
  __shared__ short Vs[Pc][HDc];   // 32 KB

  const int tid = threadIdx.x;
#pragma unroll
  for (int it = 0; it < 8; ++it) {
    int idx = tid + it * 256;          // 0..2047 -> 2048 x short8
    int p = idx >> 3, c8 = (idx & 7) * 8;
    *reinterpret_cast<s16x8*>(&Ks[p][c8]) =
        *reinterpret_cast<const s16x8*>(&Kg[base + (size_t)p * Ec + c8]);
    *reinterpret_cast<s16x8*>(&Vs[p][c8]) =
        *reinterpret_cast<const s16x8*>(&Vg[base + (size_t)p * Ec + c8]);
  }
  __syncthreads();

  const float scale = 0.125f;   // 1/sqrt(64)
  float q[HDc];
  {
    const short* qp = &Qg[base + (size_t)tid * Ec];
#pragma unroll
    for (int c = 0; c < 8; ++c) {
      s16x8 v = *reinterpret_cast<const s16x8*>(qp + c * 8);
#pragma unroll
      for (int e = 0; e < 8; ++e) q[c * 8 + e] = bf2f(v[e]) * scale;
    }
  }
  float m = -INFINITY, l = 0.f;
  float o[HDc];
#pragma unroll
  for (int d = 0; d < HDc; ++d) o[d] = 0.f;

  for (int j = 0; j < Pc; ++j) {
    float s = 0.f;
#pragma unroll
    for (int c = 0; c < 8; ++c) {
      s16x8 kv = *reinterpret_cast<const s16x8*>(&Ks[j][c * 8]);
#pragma unroll
      for (int e = 0; e < 8; ++e) s += q[c * 8 + e] * bf2f(kv[e]);
    }
    float mn   = fmaxf(m, s);
    float corr = __expf(m - mn);
    float p    = __expf(s - mn);
    l = l * corr + p;
#pragma unroll
    for (int c = 0; c < 8; ++c) {
      s16x8 vv = *reinterpret_cast<const s16x8*>(&Vs[j][c * 8]);
#pragma unroll
      for (int e = 0; e < 8; ++e)
        o[c * 8 + e] = fmaf(p, bf2f(vv[e]), o[c * 8 + e] * corr);
    }
    m = mn;
  }
  const float inv = 1.f / l;
  short* op = &Og[base + (size_t)tid * Ec];
#pragma unroll
  for (int c = 0; c < 8; ++c) {
    s16x8 v;
#pragma unroll
    for (int e = 0; e < 8; ++e) v[e] = f2bf(o[c * 8 + e] * inv);
    *reinterpret_cast<s16x8*>(op + c * 8) = v;
  }
}

// ---------------------------------------------------------------------------
// Temporal attention (causal over S=16): per (b,p) block, thread=(h,i).
// O written in-place over Q (each thread owns its (row, h-slice)).
// ---------------------------------------------------------------------------
__global__ __launch_bounds__(192)
void temporal_attn_kernel(const short* __restrict__ Qg, const short* __restrict__ Kg,
                          const short* __restrict__ Vg, short* __restrict__ Og)
{
  const int bp = blockIdx.x;           // b*256 + p
  const int b = bp >> 8, p = bp & 255;
  const int tid = threadIdx.x;
  const int h = tid >> 4, i = tid & 15;

  const float scale = 0.125f;
  auto rowoff = [&](int s) {
    return ((size_t)(b * Sc + s) * Pc + p) * Ec + (size_t)h * HDc;
  };

  float q[HDc];
  {
    const short* qp = &Qg[rowoff(i)];
#pragma unroll
    for (int c = 0; c < 8; ++c) {
      s16x8 v = *reinterpret_cast<const s16x8*>(qp + c * 8);
#pragma unroll
      for (int e = 0; e < 8; ++e) q[c * 8 + e] = bf2f(v[e]) * scale;
    }
  }
  float m = -INFINITY, l = 0.f;
  float o[HDc];
#pragma unroll
  for (int d = 0; d < HDc; ++d) o[d] = 0.f;

  for (int j = 0; j <= i; ++j) {
    const short* kp = &Kg[rowoff(j)];
    float s = 0.f;
#pragma unroll
    for (int c = 0; c < 8; ++c) {
      s16x8 kv = *reinterpret_cast<const s16x8*>(kp + c * 8);
#pragma unroll
      for (int e = 0; e < 8; ++e) s += q[c * 8 + e] * bf2f(kv[e]);
    }
    float mn   = fmaxf(m, s);
    float corr = __expf(m - mn);
    float pw   = __expf(s - mn);
    l = l * corr + pw;
    const short* vp = &Vg[rowoff(j)];
#pragma unroll
    for (int c = 0; c < 8; ++c) {
      s16x8 vv = *reinterpret_cast<const s16x8*>(vp + c * 8);
#pragma unroll
      for (int e = 0; e < 8; ++e)
        o[c * 8 + e] = fmaf(pw, bf2f(vv[e]), o[c * 8 + e] * corr);
    }
    m = mn;
  }
  const float inv = 1.f / l;
  short* op = &Og[rowoff(i)];
#pragma unroll
  for (int c = 0; c < 8; ++c) {
    s16x8 v;
#pragma unroll
    for (int e = 0; e < 8; ++e) v[e] = f2bf(o[c * 8 + e] * inv);
    *reinterpret_cast<s16x8*>(op + c * 8) = v;
  }
}

// ---------------------------------------------------------------------------
// LayerNorm over E=768: one wave per row, 4 rows per block.
// OUTBF: write bf16 (intermediate stream) or fp32 (final output).
// ---------------------------------------------------------------------------
template<bool OUTBF>
__global__ __launch_bounds__(256)
void layernorm_kernel(const float* __restrict__ U, const float* __restrict__ g,
                      const float* __restrict__ be, void* __restrict__ outv)
{
  const int tid  = threadIdx.x;
  const int lane = tid & 63, w = tid >> 6;
  const size_t row = (size_t)blockIdx.x * 4 + w;
  const float* u = U + row * Ec;

  float x[12];
#pragma unroll
  for (int c = 0; c < 3; ++c) {
    float4 v = *reinterpret_cast<const float4*>(&u[c * 256 + lane * 4]);
    x[c*4+0] = v.x; x[c*4+1] = v.y; x[c*4+2] = v.z; x[c*4+3] = v.w;
  }
  float s = 0.f;
#pragma unroll
  for (int k = 0; k < 12; ++k) s += x[k];
#pragma unroll
  for (int off = 32; off > 0; off >>= 1) s += __shfl_xor(s, off, 64);
  const float mean = s * (1.f / 768.f);

  float vs = 0.f;
#pragma unroll
  for (int k = 0; k < 12; ++k) { float d = x[k] - mean; vs += d * d; }
#pragma unroll
  for (int off = 32; off > 0; off >>= 1) vs += __shfl_xor(vs, off, 64);
  const float rs = rsqrtf(vs * (1.f / 768.f) + 1e-5f);

#pragma unroll
  for (int c = 0; c < 3; ++c) {
    int idx = c * 256 + lane * 4;
    float4 gv = *reinterpret_cast<const float4*>(&g[idx]);
    float4 bv = *reinterpret_cast<const float4*>(&be[idx]);
    float r0 = (x[c*4+0] - mean) * rs * gv.x + bv.x;
    float r1 = (x[c*4+1] - mean) * rs * gv.y + bv.y;
    float r2 = (x[c*4+2] - mean) * rs * gv.z + bv.z;
    float r3 = (x[c*4+3] - mean) * rs * gv.w + bv.w;
    if (OUTBF) {
      short* op = (short*)outv + row * Ec + idx;
      s16x4 v = { f2bf(r0), f2bf(r1), f2bf(r2), f2bf(r3) };
      *reinterpret_cast<s16x4*>(op) = v;
    } else {
      float* op = (float*)outv + row * Ec + idx;
      float4 v = make_float4(r0, r1, r2, r3);
      *reinterpret_cast<float4*>(op) = v;
    }
  }
}

// ---------------------------------------------------------------------------
extern "C" void kernel_launch(void* const* d_in, const int* in_sizes, int n_in,
                              void* d_out, int out_size, void* d_ws, size_t ws_size,
                              hipStream_t stream)
{
  const float* x       = (const float*)d_in[0];
  const float* sa_wqkv = (const float*)d_in[1];
  const float* sa_bqkv = (const float*)d_in[2];
  const float* sa_wo   = (const float*)d_in[3];
  const float* sa_bo   = (const float*)d_in[4];
  const float* sa_g    = (const float*)d_in[5];
  const float* sa_b    = (const float*)d_in[6];
  const float* ta_wqkv = (const float*)d_in[7];
  const float* ta_bqkv = (const float*)d_in[8];
  const float* ta_wo   = (const float*)d_in[9];
  const float* ta_bo   = (const float*)d_in[10];
  const float* ta_g    = (const float*)d_in[11];
  const float* ta_b    = (const float*)d_in[12];
  const float* f_w1    = (const float*)d_in[13];
  const float* f_b1    = (const float*)d_in[14];
  const float* f_w2    = (const float*)d_in[15];
  const float* f_b2    = (const float*)d_in[16];
  const float* f_g     = (const float*)d_in[17];
  const float* f_b     = (const float*)d_in[18];

  float* out = (float*)d_out;

  // ws layout: Xb (bf16, ME) | QKVH (bf16, 4*ME) | U (fp32, ME)
  // bytes: 2*ME + 8*ME + 4*ME = 14*ME = 176 MB
  const size_t need = 14 * ME;
  if (ws_size < need) return;   // clean absmax failure -> signals ws shortage

  short* Xb = (short*)d_ws;
  short* Qb = Xb + ME;
  short* Kb = Qb + ME;
  short* Vb = Qb + 2 * ME;
  short* Hb = Qb;                       // FFN hidden reuses QKVH region (4*ME)
  float* U  = (float*)(Qb + 4 * ME);

  const dim3 gemm_qkv(Mrows / 64, Ec / 64, 3);
  const dim3 gemm_sq (Mrows / 64, Ec / 64, 1);
  const dim3 gemm_ff1(Mrows / 64, FFc / 64, 1);

  // x -> bf16
  f2bf_kernel<<<(int)(ME / 8 / 256), 256, 0, stream>>>(x, Xb, (int)(ME / 8));

  // ---- Stage A: spatial attention ----
  gemm_kernel<0><<<gemm_qkv, 256, 0, stream>>>(Xb, sa_wqkv, sa_bqkv, nullptr, Qb, Mrows, Ec, Ec);
  spatial_attn_kernel<<<dim3(Bc * Sc, Hc), 256, 0, stream>>>(Qb, Kb, Vb, Qb);
  gemm_kernel<2><<<gemm_sq, 256, 0, stream>>>(Qb, sa_wo, sa_bo, x, U, Mrows, Ec, Ec);
  layernorm_kernel<true><<<Mrows / 4, 256, 0, stream>>>(U, sa_g, sa_b, Xb);

  // ---- Stage B: temporal attention ----
  gemm_kernel<0><<<gemm_qkv, 256, 0, stream>>>(Xb, ta_wqkv, ta_bqkv, nullptr, Qb, Mrows, Ec, Ec);
  temporal_attn_kernel<<<Bc * Pc, 192, 0, stream>>>(Qb, Kb, Vb, Qb);
  gemm_kernel<3><<<gemm_sq, 256, 0, stream>>>(Qb, ta_wo, ta_bo, Xb, U, Mrows, Ec, Ec);
  layernorm_kernel<true><<<Mrows / 4, 256, 0, stream>>>(U, ta_g, ta_b, Xb);

  // ---- Stage C: FFN ----
  gemm_kernel<1><<<gemm_ff1, 256, 0, stream>>>(Xb, f_w1, f_b1, nullptr, Hb, Mrows, FFc, Ec);
  gemm_kernel<3><<<gemm_sq, 256, 0, stream>>>(Hb, f_w2, f_b2, Xb, U, Mrows, Ec, FFc);
  layernorm_kernel<false><<<Mrows / 4, 256, 0, stream>>>(U, f_g, f_b, out);
}

// Round 3
// 2036.800 us; speedup vs baseline: 1.0014x; 1.0014x over previous
//
#include <hip/hip_runtime.h>
#include <hip/hip_bf16.h>
#include <math.h>

// Problem constants
constexpr int Bc = 4, Sc = 16, Pc = 256, Ec = 768, Hc = 12, HDc = 64, FFc = 3072;
constexpr int Mrows = Bc * Sc * Pc;              // 16384 token rows
constexpr size_t ME = (size_t)Mrows * Ec;        // 12,582,912 elements

typedef __attribute__((ext_vector_type(4))) float f32x4;
typedef __attribute__((ext_vector_type(8))) short s16x8;
typedef __attribute__((ext_vector_type(4))) short s16x4;

__device__ __forceinline__ short f2bf(float f) {
  union { float f; unsigned u; } v; v.f = f;
  unsigned r = (v.u + 0x7FFFu + ((v.u >> 16) & 1u)) >> 16;  // RNE
  return (short)r;
}
__device__ __forceinline__ float bf2f(short s) {
  union { unsigned u; float f; } v; v.u = ((unsigned)(unsigned short)s) << 16;
  return v.f;
}

// ---------------------------------------------------------------------------
// fp32 -> bf16 convert (vectorized, 8 elems/thread)
// ---------------------------------------------------------------------------
__global__ __launch_bounds__(256)
void f2bf_kernel(const float* __restrict__ in, short* __restrict__ out, int n8)
{
  int i = blockIdx.x * 256 + threadIdx.x;
  if (i >= n8) return;
  const float4* p = reinterpret_cast<const float4*>(in + (size_t)i * 8);
  float4 a = p[0], b = p[1];
  s16x8 o = { f2bf(a.x), f2bf(a.y), f2bf(a.z), f2bf(a.w),
              f2bf(b.x), f2bf(b.y), f2bf(b.z), f2bf(b.w) };
  *reinterpret_cast<s16x8*>(out + (size_t)i * 8) = o;
}

// ---------------------------------------------------------------------------
// GEMM: C[z] = A[M,K](bf16) * W[z][K,N](fp32->bf16) + bias[z]
// OUT: 0 = bf16 store, 1 = bf16 store + relu,
//      2 = fp32 store + fp32 residual, 3 = fp32 store + bf16 residual
// 64x64 tile, 4 waves (2x2), BK=32, bf16 MFMA 16x16x32, fp32 accum.
// ---------------------------------------------------------------------------
template<int OUT>
__global__ __launch_bounds__(256)
void gemm_kernel(const short* __restrict__ A, const float* __restrict__ Wg,
                 const float* __restrict__ biasg, const void* __restrict__ resv,
                 void* __restrict__ Cg, int M, int N, int K)
{
  const int z = blockIdx.z;
  const float* W  = Wg    + (size_t)z * K * N;
  const float* bz = biasg + (size_t)z * N;

  const int bm = blockIdx.x * 64;
  const int bn = blockIdx.y * 64;

  // stride 40 shorts = 80B rows (16B-aligned, breaks pow2 banking)
  __shared__ alignas(16) short As[64][40];
  __shared__ alignas(16) short Bs[64][40];   // Bs[n][k] (transposed)

  const int tid  = threadIdx.x;
  const int lane = tid & 63;
  const int wid  = tid >> 6;
  const int wr   = wid >> 1, wc = wid & 1;
  const int l16  = lane & 15;
  const int kb   = (lane >> 4) * 8;

  const f32x4 zero = {0.f, 0.f, 0.f, 0.f};
  f32x4 acc[2][2] = {{zero, zero}, {zero, zero}};

  for (int k0 = 0; k0 < K; k0 += 32) {
    // stage A tile: 64 rows x 32 k, bf16, 256 threads x 16B
    {
      int r = tid >> 2, c8 = (tid & 3) * 8;
      *reinterpret_cast<s16x8*>(&As[r][c8]) =
          *reinterpret_cast<const s16x8*>(&A[(size_t)(bm + r) * K + k0 + c8]);
    }
    // stage B tile transposed: Bs[n][k] = bf16(W[k0+k][bn+n])
#pragma unroll
    for (int it = 0; it < 2; ++it) {
      int i = tid + it * 256;
      int k = i >> 4, c4 = i & 15;
      float4 v = *reinterpret_cast<const float4*>(&W[(size_t)(k0 + k) * N + bn + c4 * 4]);
      Bs[c4 * 4 + 0][k] = f2bf(v.x);
      Bs[c4 * 4 + 1][k] = f2bf(v.y);
      Bs[c4 * 4 + 2][k] = f2bf(v.z);
      Bs[c4 * 4 + 3][k] = f2bf(v.w);
    }
    __syncthreads();

    s16x8 a[2], b[2];
#pragma unroll
    for (int m = 0; m < 2; ++m)
      a[m] = *reinterpret_cast<const s16x8*>(&As[wr * 32 + m * 16 + l16][kb]);
#pragma unroll
    for (int n = 0; n < 2; ++n)
      b[n] = *reinterpret_cast<const s16x8*>(&Bs[wc * 32 + n * 16 + l16][kb]);
#pragma unroll
    for (int m = 0; m < 2; ++m)
#pragma unroll
      for (int n = 0; n < 2; ++n)
        acc[m][n] = __builtin_amdgcn_mfma_f32_16x16x32_bf16(a[m], b[n], acc[m][n], 0, 0, 0);
    __syncthreads();
  }

  const float* resf = (const float*)resv;
  const short* resb = (const short*)resv;
  short* Cb = (short*)Cg + (size_t)z * (size_t)M * N;
  float* Cf = (float*)Cg + (size_t)z * (size_t)M * N;

#pragma unroll
  for (int m = 0; m < 2; ++m)
#pragma unroll
    for (int n = 0; n < 2; ++n) {
      const int row0 = bm + wr * 32 + m * 16 + (lane >> 4) * 4;
      const int col  = bn + wc * 32 + n * 16 + l16;
#pragma unroll
      for (int r = 0; r < 4; ++r) {
        float v = acc[m][n][r] + bz[col];
        size_t idx = (size_t)(row0 + r) * N + col;
        if (OUT == 2) v += resf[idx];
        if (OUT == 3) v += bf2f(resb[idx]);
        if (OUT == 1) v = fmaxf(v, 0.f);
        if (OUT <= 1) Cb[idx] = f2bf(v);
        else          Cf[idx] = v;
      }
    }
}

// ---------------------------------------------------------------------------
// Spatial attention: per (b*S+s, h) block; 256 threads = 256 query rows.
// K and V staged in LDS (bf16, 32KB each); online softmax; O in-place over Q.
// ---------------------------------------------------------------------------
__global__ __launch_bounds__(256)
void spatial_attn_kernel(const short* __restrict__ Qg, const short* __restrict__ Kg,
                         const short* __restrict__ Vg, short* __restrict__ Og)
{
  const int bs = blockIdx.x;   // 0..63 (b*S+s)
  const int h  = blockIdx.y;   // 0..11
  const size_t base = (size_t)bs * Pc * Ec + (size_t)h * HDc;

  __shared__ short Ks[Pc][HDc];   // 32 KB
  __shared__ short Vs[Pc][HDc];   // 32 KB

  const int tid = threadIdx.x;
#pragma unroll
  for (int it = 0; it < 8; ++it) {
    int idx = tid + it * 256;          // 0..2047 -> 2048 x short8
    int p = idx >> 3, c8 = (idx & 7) * 8;
    *reinterpret_cast<s16x8*>(&Ks[p][c8]) =
        *reinterpret_cast<const s16x8*>(&Kg[base + (size_t)p * Ec + c8]);
    *reinterpret_cast<s16x8*>(&Vs[p][c8]) =
        *reinterpret_cast<const s16x8*>(&Vg[base + (size_t)p * Ec + c8]);
  }
  __syncthreads();

  const float scale = 0.125f;   // 1/sqrt(64)
  float q[HDc];
  {
    const short* qp = &Qg[base + (size_t)tid * Ec];
#pragma unroll
    for (int c = 0; c < 8; ++c) {
      s16x8 v = *reinterpret_cast<const s16x8*>(qp + c * 8);
#pragma unroll
      for (int e = 0; e < 8; ++e) q[c * 8 + e] = bf2f(v[e]) * scale;
    }
  }
  float m = -INFINITY, l = 0.f;
  float o[HDc];
#pragma unroll
  for (int d = 0; d < HDc; ++d) o[d] = 0.f;

  for (int j = 0; j < Pc; ++j) {
    float s = 0.f;
#pragma unroll
    for (int c = 0; c < 8; ++c) {
      s16x8 kv = *reinterpret_cast<const s16x8*>(&Ks[j][c * 8]);
#pragma unroll
      for (int e = 0; e < 8; ++e) s += q[c * 8 + e] * bf2f(kv[e]);
    }
    float mn   = fmaxf(m, s);
    float corr = __expf(m - mn);
    float p    = __expf(s - mn);
    l = l * corr + p;
#pragma unroll
    for (int c = 0; c < 8; ++c) {
      s16x8 vv = *reinterpret_cast<const s16x8*>(&Vs[j][c * 8]);
#pragma unroll
      for (int e = 0; e < 8; ++e)
        o[c * 8 + e] = fmaf(p, bf2f(vv[e]), o[c * 8 + e] * corr);
    }
    m = mn;
  }
  const float inv = 1.f / l;
  short* op = &Og[base + (size_t)tid * Ec];
#pragma unroll
  for (int c = 0; c < 8; ++c) {
    s16x8 v;
#pragma unroll
    for (int e = 0; e < 8; ++e) v[e] = f2bf(o[c * 8 + e] * inv);
    *reinterpret_cast<s16x8*>(op + c * 8) = v;
  }
}

// ---------------------------------------------------------------------------
// Temporal attention (causal over S=16): per (b,p) block, thread=(h,i).
// O written in-place over Q (each thread owns its (row, h-slice)).
// ---------------------------------------------------------------------------
__global__ __launch_bounds__(192)
void temporal_attn_kernel(const short* __restrict__ Qg, const short* __restrict__ Kg,
                          const short* __restrict__ Vg, short* __restrict__ Og)
{
  const int bp = blockIdx.x;           // b*256 + p
  const int b = bp >> 8, p = bp & 255;
  const int tid = threadIdx.x;
  const int h = tid >> 4, i = tid & 15;

  const float scale = 0.125f;
  auto rowoff = [&](int s) {
    return ((size_t)(b * Sc + s) * Pc + p) * Ec + (size_t)h * HDc;
  };

  float q[HDc];
  {
    const short* qp = &Qg[rowoff(i)];
#pragma unroll
    for (int c = 0; c < 8; ++c) {
      s16x8 v = *reinterpret_cast<const s16x8*>(qp + c * 8);
#pragma unroll
      for (int e = 0; e < 8; ++e) q[c * 8 + e] = bf2f(v[e]) * scale;
    }
  }
  float m = -INFINITY, l = 0.f;
  float o[HDc];
#pragma unroll
  for (int d = 0; d < HDc; ++d) o[d] = 0.f;

  for (int j = 0; j <= i; ++j) {
    const short* kp = &Kg[rowoff(j)];
    float s = 0.f;
#pragma unroll
    for (int c = 0; c < 8; ++c) {
      s16x8 kv = *reinterpret_cast<const s16x8*>(kp + c * 8);
#pragma unroll
      for (int e = 0; e < 8; ++e) s += q[c * 8 + e] * bf2f(kv[e]);
    }
    float mn   = fmaxf(m, s);
    float corr = __expf(m - mn);
    float pw   = __expf(s - mn);
    l = l * corr + pw;
    const short* vp = &Vg[rowoff(j)];
#pragma unroll
    for (int c = 0; c < 8; ++c) {
      s16x8 vv = *reinterpret_cast<const s16x8*>(vp + c * 8);
#pragma unroll
      for (int e = 0; e < 8; ++e)
        o[c * 8 + e] = fmaf(pw, bf2f(vv[e]), o[c * 8 + e] * corr);
    }
    m = mn;
  }
  const float inv = 1.f / l;
  short* op = &Og[rowoff(i)];
#pragma unroll
  for (int c = 0; c < 8; ++c) {
    s16x8 v;
#pragma unroll
    for (int e = 0; e < 8; ++e) v[e] = f2bf(o[c * 8 + e] * inv);
    *reinterpret_cast<s16x8*>(op + c * 8) = v;
  }
}

// ---------------------------------------------------------------------------
// LayerNorm over E=768: one wave per row, 4 rows per block.
// OUTBF: write bf16 (intermediate stream) or fp32 (final output).
// ---------------------------------------------------------------------------
template<bool OUTBF>
__global__ __launch_bounds__(256)
void layernorm_kernel(const float* __restrict__ U, const float* __restrict__ g,
                      const float* __restrict__ be, void* __restrict__ outv)
{
  const int tid  = threadIdx.x;
  const int lane = tid & 63, w = tid >> 6;
  const size_t row = (size_t)blockIdx.x * 4 + w;
  const float* u = U + row * Ec;

  float x[12];
#pragma unroll
  for (int c = 0; c < 3; ++c) {
    float4 v = *reinterpret_cast<const float4*>(&u[c * 256 + lane * 4]);
    x[c*4+0] = v.x; x[c*4+1] = v.y; x[c*4+2] = v.z; x[c*4+3] = v.w;
  }
  float s = 0.f;
#pragma unroll
  for (int k = 0; k < 12; ++k) s += x[k];
#pragma unroll
  for (int off = 32; off > 0; off >>= 1) s += __shfl_xor(s, off, 64);
  const float mean = s * (1.f / 768.f);

  float vs = 0.f;
#pragma unroll
  for (int k = 0; k < 12; ++k) { float d = x[k] - mean; vs += d * d; }
#pragma unroll
  for (int off = 32; off > 0; off >>= 1) vs += __shfl_xor(vs, off, 64);
  const float rs = rsqrtf(vs * (1.f / 768.f) + 1e-5f);

#pragma unroll
  for (int c = 0; c < 3; ++c) {
    int idx = c * 256 + lane * 4;
    float4 gv = *reinterpret_cast<const float4*>(&g[idx]);
    float4 bv = *reinterpret_cast<const float4*>(&be[idx]);
    float r0 = (x[c*4+0] - mean) * rs * gv.x + bv.x;
    float r1 = (x[c*4+1] - mean) * rs * gv.y + bv.y;
    float r2 = (x[c*4+2] - mean) * rs * gv.z + bv.z;
    float r3 = (x[c*4+3] - mean) * rs * gv.w + bv.w;
    if (OUTBF) {
      short* op = (short*)outv + row * Ec + idx;
      s16x4 v = { f2bf(r0), f2bf(r1), f2bf(r2), f2bf(r3) };
      *reinterpret_cast<s16x4*>(op) = v;
    } else {
      float* op = (float*)outv + row * Ec + idx;
      float4 v = make_float4(r0, r1, r2, r3);
      *reinterpret_cast<float4*>(op) = v;
    }
  }
}

// ---------------------------------------------------------------------------
extern "C" void kernel_launch(void* const* d_in, const int* in_sizes, int n_in,
                              void* d_out, int out_size, void* d_ws, size_t ws_size,
                              hipStream_t stream)
{
  const float* x       = (const float*)d_in[0];
  const float* sa_wqkv = (const float*)d_in[1];
  const float* sa_bqkv = (const float*)d_in[2];
  const float* sa_wo   = (const float*)d_in[3];
  const float* sa_bo   = (const float*)d_in[4];
  const float* sa_g    = (const float*)d_in[5];
  const float* sa_b    = (const float*)d_in[6];
  const float* ta_wqkv = (const float*)d_in[7];
  const float* ta_bqkv = (const float*)d_in[8];
  const float* ta_wo   = (const float*)d_in[9];
  const float* ta_bo   = (const float*)d_in[10];
  const float* ta_g    = (const float*)d_in[11];
  const float* ta_b    = (const float*)d_in[12];
  const float* f_w1    = (const float*)d_in[13];
  const float* f_b1    = (const float*)d_in[14];
  const float* f_w2    = (const float*)d_in[15];
  const float* f_b2    = (const float*)d_in[16];
  const float* f_g     = (const float*)d_in[17];
  const float* f_b     = (const float*)d_in[18];

  float* out = (float*)d_out;

  // ws layout: Xb (bf16, ME) | QKVH (bf16, 4*ME) | U (fp32, ME)
  // bytes: 2*ME + 8*ME + 4*ME = 14*ME = 176 MB
  const size_t need = 14 * ME;
  if (ws_size < need) return;   // clean absmax failure -> signals ws shortage

  short* Xb = (short*)d_ws;
  short* Qb = Xb + ME;
  short* Kb = Qb + ME;
  short* Vb = Qb + 2 * ME;
  short* Hb = Qb;                       // FFN hidden reuses QKVH region (4*ME)
  float* U  = (float*)(Qb + 4 * ME);

  const dim3 gemm_qkv(Mrows / 64, Ec / 64, 3);
  const dim3 gemm_sq (Mrows / 64, Ec / 64, 1);
  const dim3 gemm_ff1(Mrows / 64, FFc / 64, 1);

  // x -> bf16
  f2bf_kernel<<<(int)(ME / 8 / 256), 256, 0, stream>>>(x, Xb, (int)(ME / 8));

  // ---- Stage A: spatial attention ----
  gemm_kernel<0><<<gemm_qkv, 256, 0, stream>>>(Xb, sa_wqkv, sa_bqkv, nullptr, Qb, Mrows, Ec, Ec);
  spatial_attn_kernel<<<dim3(Bc * Sc, Hc), 256, 0, stream>>>(Qb, Kb, Vb, Qb);
  gemm_kernel<2><<<gemm_sq, 256, 0, stream>>>(Qb, sa_wo, sa_bo, x, U, Mrows, Ec, Ec);
  layernorm_kernel<true><<<Mrows / 4, 256, 0, stream>>>(U, sa_g, sa_b, Xb);

  // ---- Stage B: temporal attention ----
  gemm_kernel<0><<<gemm_qkv, 256, 0, stream>>>(Xb, ta_wqkv, ta_bqkv, nullptr, Qb, Mrows, Ec, Ec);
  temporal_attn_kernel<<<Bc * Pc, 192, 0, stream>>>(Qb, Kb, Vb, Qb);
  gemm_kernel<3><<<gemm_sq, 256, 0, stream>>>(Qb, ta_wo, ta_bo, Xb, U, Mrows, Ec, Ec);
  layernorm_kernel<true><<<Mrows / 4, 256, 0, stream>>>(U, ta_g, ta_b, Xb);

  // ---- Stage C: FFN ----
  gemm_kernel<1><<<gemm_ff1, 256, 0, stream>>>(Xb, f_w1, f_b1, nullptr, Hb, Mrows, FFc, Ec);
  gemm_kernel<3><<<gemm_sq, 256, 0, stream>>>(Hb, f_w2, f_b2, Xb, U, Mrows, Ec, FFc);
  layernorm_kernel<false><<<Mrows / 4, 256, 0, stream>>>(U, f_g, f_b, out);
}

// Round 4
// 758.476 us; speedup vs baseline: 2.6891x; 2.6854x over previous
//
#include <hip/hip_runtime.h>
#include <hip/hip_bf16.h>
#include <math.h>

// Problem constants
constexpr int Bc = 4, Sc = 16, Pc = 256, Ec = 768, Hc = 12, HDc = 64, FFc = 3072;
constexpr int Mrows = Bc * Sc * Pc;              // 16384 token rows
constexpr size_t ME = (size_t)Mrows * Ec;        // 12,582,912 elements

typedef __attribute__((ext_vector_type(4))) float f32x4;
typedef __attribute__((ext_vector_type(8))) short s16x8;
typedef __attribute__((ext_vector_type(4))) short s16x4;

__device__ __forceinline__ short f2bf(float f) {
  union { float f; unsigned u; } v; v.f = f;
  unsigned r = (v.u + 0x7FFFu + ((v.u >> 16) & 1u)) >> 16;  // RNE
  return (short)r;
}
__device__ __forceinline__ float bf2f(short s) {
  union { unsigned u; float f; } v; v.u = ((unsigned)(unsigned short)s) << 16;
  return v.f;
}

// async global->LDS, 16B per lane; lds dest must be wave-uniform base.
__device__ __forceinline__ void async16(const void* g, void* l) {
  __builtin_amdgcn_global_load_lds(
      (const __attribute__((address_space(1))) unsigned int*)g,
      (__attribute__((address_space(3))) unsigned int*)l, 16, 0, 0);
}

// ---------------------------------------------------------------------------
// fp32 -> bf16 convert (vectorized, 8 elems/thread)
// ---------------------------------------------------------------------------
__global__ __launch_bounds__(256)
void f2bf_kernel(const float* __restrict__ in, short* __restrict__ out, int n8)
{
  int i = blockIdx.x * 256 + threadIdx.x;
  if (i >= n8) return;
  const float4* p = reinterpret_cast<const float4*>(in + (size_t)i * 8);
  float4 a = p[0], b = p[1];
  s16x8 o = { f2bf(a.x), f2bf(a.y), f2bf(a.z), f2bf(a.w),
              f2bf(b.x), f2bf(b.y), f2bf(b.z), f2bf(b.w) };
  *reinterpret_cast<s16x8*>(out + (size_t)i * 8) = o;
}

// ---------------------------------------------------------------------------
// Weight transpose-convert: W fp32 [K][N] -> Wt bf16 [N][K].
// Register-blocked 64x64 tile, coalesced reads (16 lanes share a 64B line)
// and coalesced 32B writes. No LDS.
// ---------------------------------------------------------------------------
__global__ __launch_bounds__(256)
void wtrans_kernel(const float* __restrict__ Wg, short* __restrict__ Wtg,
                   int K, int N)
{
  const int z = blockIdx.z;
  const float* W  = Wg  + (size_t)z * K * N;
  short*       Wt = Wtg + (size_t)z * N * K;
  const int n0 = blockIdx.x * 64, k0 = blockIdx.y * 64;
  const int t = threadIdx.x;
  const int n  = n0 + (t >> 2);
  const int kc = k0 + (t & 3) * 16;
  short buf[16];
#pragma unroll
  for (int i = 0; i < 16; ++i)
    buf[i] = f2bf(W[(size_t)(kc + i) * N + n]);
  *reinterpret_cast<s16x8*>(&Wt[(size_t)n * K + kc])     = *reinterpret_cast<s16x8*>(&buf[0]);
  *reinterpret_cast<s16x8*>(&Wt[(size_t)n * K + kc + 8]) = *reinterpret_cast<s16x8*>(&buf[8]);
}

// ---------------------------------------------------------------------------
// GEMM (m97 structure): C = A[M,K](bf16) * Wt[z][N,K](bf16)^T + bias[z]
// 128x128 tile, 4 waves (2x2), each wave 64x64 (4x4 frags), BK=32,
// global_load_lds width-16 staging, 16x16x32 bf16 MFMA.
// OUT: 0 bf16 | 1 bf16+relu | 2 f32 + f32 residual | 3 f32 + bf16 residual
//      4 QKV-A mode: z<2 bf16 normal, z==2 writes transposed-V layout to vt
// ---------------------------------------------------------------------------
template<int OUT>
__global__ __launch_bounds__(256, 3)
void gemm_kernel(const short* __restrict__ A, const short* __restrict__ Wt,
                 const float* __restrict__ biasg, const void* __restrict__ resv,
                 void* __restrict__ Cg, short* __restrict__ vt,
                 int M, int N, int K)
{
  const int z = blockIdx.z;
  const short* Wz = Wt + (size_t)z * (size_t)N * K;
  const float* bz = biasg + (size_t)z * N;

  const int bm = blockIdx.x * 128;
  const int bn = blockIdx.y * 128;

  __shared__ short As[128 * 32];   // 8KB, linear rows of 64B
  __shared__ short Bs[128 * 32];   // 8KB

  const int tid  = threadIdx.x;
  const int lane = tid & 63;
  const int wid  = tid >> 6;
  const int wr   = wid >> 1, wc = wid & 1;
  const int l16  = lane & 15;
  const int g    = lane >> 4;
  const int srow = lane >> 2, scol = (lane & 3) * 8;  // staging: 4 lanes/row

  f32x4 acc[4][4];
#pragma unroll
  for (int m = 0; m < 4; ++m)
#pragma unroll
    for (int n = 0; n < 4; ++n) acc[m][n] = f32x4{0.f, 0.f, 0.f, 0.f};

  for (int k0 = 0; k0 < K; k0 += 32) {
#pragma unroll
    for (int is = 0; is < 2; ++is) {
      const int c = is * 4 + wid;          // chunk: 1KB = 16 rows
      const int row = c * 16 + srow;
      async16(&A[(size_t)(bm + row) * K + k0 + scol],  (char*)As + c * 1024);
      async16(&Wz[(size_t)(bn + row) * K + k0 + scol], (char*)Bs + c * 1024);
    }
    __syncthreads();

    s16x8 af[4], bf[4];
#pragma unroll
    for (int m = 0; m < 4; ++m)
      af[m] = *reinterpret_cast<const s16x8*>(
          (const char*)As + (wr * 64 + m * 16 + l16) * 64 + g * 16);
#pragma unroll
    for (int n = 0; n < 4; ++n)
      bf[n] = *reinterpret_cast<const s16x8*>(
          (const char*)Bs + (wc * 64 + n * 16 + l16) * 64 + g * 16);
#pragma unroll
    for (int m = 0; m < 4; ++m)
#pragma unroll
      for (int n = 0; n < 4; ++n)
        acc[m][n] = __builtin_amdgcn_mfma_f32_16x16x32_bf16(af[m], bf[n], acc[m][n], 0, 0, 0);
    __syncthreads();
  }

  const float* resf = (const float*)resv;
  const short* resb = (const short*)resv;
  short* Cb = (short*)Cg + (size_t)z * (size_t)M * N;
  float* Cf = (float*)Cg + (size_t)z * (size_t)M * N;

#pragma unroll
  for (int m = 0; m < 4; ++m) {
    const int row0 = bm + wr * 64 + m * 16 + g * 4;
#pragma unroll
    for (int n = 0; n < 4; ++n) {
      const int col = bn + wc * 64 + n * 16 + l16;
      if (OUT == 4 && z == 2) {
        // transposed-V: Vt[(bs*12+h)*64 + d][p], 4 consecutive p per lane
        const int bs2 = row0 >> 8, p0 = row0 & 255;
        const int h2 = col >> 6,  d2 = col & 63;
        const float bias = bz[col];
        s16x4 v = { f2bf(acc[m][n][0] + bias), f2bf(acc[m][n][1] + bias),
                    f2bf(acc[m][n][2] + bias), f2bf(acc[m][n][3] + bias) };
        *reinterpret_cast<s16x4*>(
            &vt[(((size_t)bs2 * 12 + h2) * 64 + d2) * 256 + p0]) = v;
      } else {
        const float bias = bz[col];
#pragma unroll
        for (int r = 0; r < 4; ++r) {
          float v = acc[m][n][r] + bias;
          size_t idx = (size_t)(row0 + r) * N + col;
          if (OUT == 2) v += resf[idx];
          if (OUT == 3) v += bf2f(resb[idx]);
          if (OUT == 1) v = fmaxf(v, 0.f);
          if (OUT == 2 || OUT == 3) Cf[idx] = v;
          else                      Cb[idx] = f2bf(v);
        }
      }
    }
  }
}

// ---------------------------------------------------------------------------
// Spatial attention, MFMA flash: block = (b*S+s, h), 4 waves x 64 queries.
// K staged in LDS (XOR-swizzled via pre-swizzled global_load_lds source),
// P per-wave in swizzled LDS, V read as B-frags from pre-transposed Vt.
// ---------------------------------------------------------------------------
__global__ __launch_bounds__(256, 2)
void spatial_attn_kernel(const short* __restrict__ Qg, const short* __restrict__ Kg,
                         const short* __restrict__ Vt, short* __restrict__ Og)
{
  const int bs = blockIdx.x;   // 0..63
  const int h  = blockIdx.y;   // 0..11

  __shared__ short Ks[256 * 64];      // 32KB, swizzled rows of 128B
  __shared__ short Pl[4 * 64 * 64];   // 32KB, per-wave 8KB P buffer

  const int tid  = threadIdx.x;
  const int lane = tid & 63;
  const int wid  = tid >> 6;
  const int l16  = lane & 15;
  const int g    = lane >> 4;
  const int q0   = wid * 64;
  char* Pw = (char*)Pl + wid * 8192;

  // stage K: 32KB = 32 chunks of 1KB; source col pre-swizzled (T2 both-sides)
#pragma unroll
  for (int is = 0; is < 8; ++is) {
    const int c = is * 4 + wid;
    const int row = c * 8 + (lane >> 3);
    const int sl  = lane & 7;
    const int col8 = sl ^ (row & 7);
    async16(&Kg[(size_t)(bs * 256 + row) * 768 + h * 64 + col8 * 8],
            (char*)Ks + c * 1024);
  }

  // Q fragments (per-lane 16B global loads), held in registers
  s16x8 qa[4][2];
#pragma unroll
  for (int m = 0; m < 4; ++m)
#pragma unroll
    for (int ks = 0; ks < 2; ++ks)
      qa[m][ks] = *reinterpret_cast<const s16x8*>(
          &Qg[(size_t)(bs * 256 + q0 + m * 16 + l16) * 768 + h * 64 + ks * 32 + g * 8]);

  __syncthreads();

  float mrun[4][4], lrun[4][4];
  f32x4 oac[4][4];
#pragma unroll
  for (int m = 0; m < 4; ++m)
#pragma unroll
    for (int r = 0; r < 4; ++r) { mrun[m][r] = -INFINITY; lrun[m][r] = 0.f; }
#pragma unroll
  for (int m = 0; m < 4; ++m)
#pragma unroll
    for (int n = 0; n < 4; ++n) oac[m][n] = f32x4{0.f, 0.f, 0.f, 0.f};

  const size_t vbase = ((size_t)bs * 12 + h) * 64 * 256;

  for (int t = 0; t < 4; ++t) {
    const int key0 = t * 64;
    // S = Q K^T (64q x 64k per wave)
    f32x4 sc[4][4];
#pragma unroll
    for (int m = 0; m < 4; ++m)
#pragma unroll
      for (int n = 0; n < 4; ++n) sc[m][n] = f32x4{0.f, 0.f, 0.f, 0.f};
#pragma unroll
    for (int ks = 0; ks < 2; ++ks) {
      s16x8 kf[4];
#pragma unroll
      for (int n = 0; n < 4; ++n) {
        const int row = key0 + n * 16 + l16;
        const int s = ks * 4 + g;
        kf[n] = *reinterpret_cast<const s16x8*>(
            (const char*)Ks + row * 128 + ((s ^ (row & 7)) * 16));
      }
#pragma unroll
      for (int m = 0; m < 4; ++m)
#pragma unroll
        for (int n = 0; n < 4; ++n)
          sc[m][n] = __builtin_amdgcn_mfma_f32_16x16x32_bf16(qa[m][ks], kf[n], sc[m][n], 0, 0, 0);
    }
    // scale
#pragma unroll
    for (int m = 0; m < 4; ++m)
#pragma unroll
      for (int n = 0; n < 4; ++n)
#pragma unroll
        for (int r = 0; r < 4; ++r) sc[m][n][r] *= 0.125f;

    // online softmax (row reduce across n-frags + 16-lane groups)
#pragma unroll
    for (int m = 0; m < 4; ++m) {
#pragma unroll
      for (int r = 0; r < 4; ++r) {
        float mx = fmaxf(fmaxf(sc[m][0][r], sc[m][1][r]), fmaxf(sc[m][2][r], sc[m][3][r]));
#pragma unroll
        for (int mk = 1; mk < 16; mk <<= 1) mx = fmaxf(mx, __shfl_xor(mx, mk, 64));
        const float mnew = fmaxf(mrun[m][r], mx);
        const float corr = __expf(mrun[m][r] - mnew);
        mrun[m][r] = mnew;
        float rs = 0.f;
#pragma unroll
        for (int n = 0; n < 4; ++n) {
          float p = __expf(sc[m][n][r] - mnew);
          sc[m][n][r] = p;
          rs += p;
        }
#pragma unroll
        for (int mk = 1; mk < 16; mk <<= 1) rs += __shfl_xor(rs, mk, 64);
        lrun[m][r] = lrun[m][r] * corr + rs;
#pragma unroll
        for (int nd = 0; nd < 4; ++nd) oac[m][nd][r] *= corr;
      }
    }
    // P -> per-wave LDS (bf16, swizzled)
#pragma unroll
    for (int m = 0; m < 4; ++m)
#pragma unroll
      for (int n = 0; n < 4; ++n)
#pragma unroll
        for (int r = 0; r < 4; ++r) {
          const int q = m * 16 + g * 4 + r;
          const int key = n * 16 + l16;
          const int byte = q * 128 + (((key >> 3) ^ (q & 7)) * 16) + (key & 7) * 2;
          *reinterpret_cast<short*>(Pw + byte) = f2bf(sc[m][n][r]);
        }
    // O += P V  (V from global Vt, L1/L2-resident slab)
#pragma unroll
    for (int ks = 0; ks < 2; ++ks) {
      s16x8 pa[4], vf[4];
#pragma unroll
      for (int m = 0; m < 4; ++m) {
        const int q = m * 16 + l16;
        const int s = ks * 4 + g;
        pa[m] = *reinterpret_cast<const s16x8*>(Pw + q * 128 + ((s ^ (q & 7)) * 16));
      }
#pragma unroll
      for (int nd = 0; nd < 4; ++nd) {
        const int d = nd * 16 + l16;
        const int key = key0 + ks * 32 + g * 8;
        vf[nd] = *reinterpret_cast<const s16x8*>(&Vt[vbase + (size_t)d * 256 + key]);
      }
#pragma unroll
      for (int m = 0; m < 4; ++m)
#pragma unroll
        for (int nd = 0; nd < 4; ++nd)
          oac[m][nd] = __builtin_amdgcn_mfma_f32_16x16x32_bf16(pa[m], vf[nd], oac[m][nd], 0, 0, 0);
    }
  }

  // normalize, stage O through per-wave LDS, vectorized global write
#pragma unroll
  for (int m = 0; m < 4; ++m)
#pragma unroll
    for (int r = 0; r < 4; ++r) {
      const float inv = 1.f / lrun[m][r];
#pragma unroll
      for (int nd = 0; nd < 4; ++nd) oac[m][nd][r] *= inv;
    }
#pragma unroll
  for (int m = 0; m < 4; ++m)
#pragma unroll
    for (int nd = 0; nd < 4; ++nd)
#pragma unroll
      for (int r = 0; r < 4; ++r) {
        const int q = m * 16 + g * 4 + r;
        const int d = nd * 16 + l16;
        const int byte = q * 128 + (((d >> 3) ^ (q & 7)) * 16) + (d & 7) * 2;
        *reinterpret_cast<short*>(Pw + byte) = f2bf(oac[m][nd][r]);
      }
#pragma unroll
  for (int it = 0; it < 8; ++it) {
    const int slot = it * 64 + lane;
    const int q = slot >> 3, sl = slot & 7;
    const int d0 = (sl ^ (q & 7)) * 8;
    s16x8 v = *reinterpret_cast<const s16x8*>(Pw + slot * 16);
    *reinterpret_cast<s16x8*>(
        &Og[(size_t)(bs * 256 + q0 + q) * 768 + h * 64 + d0]) = v;
  }
}

// ---------------------------------------------------------------------------
// Temporal attention (causal over S=16): per (b,p) block, thread=(h,i).
// ---------------------------------------------------------------------------
__global__ __launch_bounds__(192)
void temporal_attn_kernel(const short* __restrict__ Qg, const short* __restrict__ Kg,
                          const short* __restrict__ Vg, short* __restrict__ Og)
{
  const int bp = blockIdx.x;
  const int b = bp >> 8, p = bp & 255;
  const int tid = threadIdx.x;
  const int h = tid >> 4, i = tid & 15;

  const float scale = 0.125f;
  auto rowoff = [&](int s) {
    return ((size_t)(b * Sc + s) * Pc + p) * Ec + (size_t)h * HDc;
  };

  float q[HDc];
  {
    const short* qp = &Qg[rowoff(i)];
#pragma unroll
    for (int c = 0; c < 8; ++c) {
      s16x8 v = *reinterpret_cast<const s16x8*>(qp + c * 8);
#pragma unroll
      for (int e = 0; e < 8; ++e) q[c * 8 + e] = bf2f(v[e]) * scale;
    }
  }
  float m = -INFINITY, l = 0.f;
  float o[HDc];
#pragma unroll
  for (int d = 0; d < HDc; ++d) o[d] = 0.f;

  for (int j = 0; j <= i; ++j) {
    const short* kp = &Kg[rowoff(j)];
    float s = 0.f;
#pragma unroll
    for (int c = 0; c < 8; ++c) {
      s16x8 kv = *reinterpret_cast<const s16x8*>(kp + c * 8);
#pragma unroll
      for (int e = 0; e < 8; ++e) s += q[c * 8 + e] * bf2f(kv[e]);
    }
    float mn   = fmaxf(m, s);
    float corr = __expf(m - mn);
    float pw   = __expf(s - mn);
    l = l * corr + pw;
    const short* vp = &Vg[rowoff(j)];
#pragma unroll
    for (int c = 0; c < 8; ++c) {
      s16x8 vv = *reinterpret_cast<const s16x8*>(vp + c * 8);
#pragma unroll
      for (int e = 0; e < 8; ++e)
        o[c * 8 + e] = fmaf(pw, bf2f(vv[e]), o[c * 8 + e] * corr);
    }
    m = mn;
  }
  const float inv = 1.f / l;
  short* op = &Og[rowoff(i)];
#pragma unroll
  for (int c = 0; c < 8; ++c) {
    s16x8 v;
#pragma unroll
    for (int e = 0; e < 8; ++e) v[e] = f2bf(o[c * 8 + e] * inv);
    *reinterpret_cast<s16x8*>(op + c * 8) = v;
  }
}

// ---------------------------------------------------------------------------
// LayerNorm over E=768: one wave per row, 4 rows per block.
// ---------------------------------------------------------------------------
template<bool OUTBF>
__global__ __launch_bounds__(256)
void layernorm_kernel(const float* __restrict__ U, const float* __restrict__ g,
                      const float* __restrict__ be, void* __restrict__ outv)
{
  const int tid  = threadIdx.x;
  const int lane = tid & 63, w = tid >> 6;
  const size_t row = (size_t)blockIdx.x * 4 + w;
  const float* u = U + row * Ec;

  float x[12];
#pragma unroll
  for (int c = 0; c < 3; ++c) {
    float4 v = *reinterpret_cast<const float4*>(&u[c * 256 + lane * 4]);
    x[c*4+0] = v.x; x[c*4+1] = v.y; x[c*4+2] = v.z; x[c*4+3] = v.w;
  }
  float s = 0.f;
#pragma unroll
  for (int k = 0; k < 12; ++k) s += x[k];
#pragma unroll
  for (int off = 32; off > 0; off >>= 1) s += __shfl_xor(s, off, 64);
  const float mean = s * (1.f / 768.f);

  float vs = 0.f;
#pragma unroll
  for (int k = 0; k < 12; ++k) { float d = x[k] - mean; vs += d * d; }
#pragma unroll
  for (int off = 32; off > 0; off >>= 1) vs += __shfl_xor(vs, off, 64);
  const float rs = rsqrtf(vs * (1.f / 768.f) + 1e-5f);

#pragma unroll
  for (int c = 0; c < 3; ++c) {
    int idx = c * 256 + lane * 4;
    float4 gv = *reinterpret_cast<const float4*>(&g[idx]);
    float4 bv = *reinterpret_cast<const float4*>(&be[idx]);
    float r0 = (x[c*4+0] - mean) * rs * gv.x + bv.x;
    float r1 = (x[c*4+1] - mean) * rs * gv.y + bv.y;
    float r2 = (x[c*4+2] - mean) * rs * gv.z + bv.z;
    float r3 = (x[c*4+3] - mean) * rs * gv.w + bv.w;
    if (OUTBF) {
      short* op = (short*)outv + row * Ec + idx;
      s16x4 v = { f2bf(r0), f2bf(r1), f2bf(r2), f2bf(r3) };
      *reinterpret_cast<s16x4*>(op) = v;
    } else {
      float* op = (float*)outv + row * Ec + idx;
      *reinterpret_cast<float4*>(op) = make_float4(r0, r1, r2, r3);
    }
  }
}

// ---------------------------------------------------------------------------
extern "C" void kernel_launch(void* const* d_in, const int* in_sizes, int n_in,
                              void* d_out, int out_size, void* d_ws, size_t ws_size,
                              hipStream_t stream)
{
  const float* x       = (const float*)d_in[0];
  const float* sa_wqkv = (const float*)d_in[1];
  const float* sa_bqkv = (const float*)d_in[2];
  const float* sa_wo   = (const float*)d_in[3];
  const float* sa_bo   = (const float*)d_in[4];
  const float* sa_g    = (const float*)d_in[5];
  const float* sa_b    = (const float*)d_in[6];
  const float* ta_wqkv = (const float*)d_in[7];
  const float* ta_bqkv = (const float*)d_in[8];
  const float* ta_wo   = (const float*)d_in[9];
  const float* ta_bo   = (const float*)d_in[10];
  const float* ta_g    = (const float*)d_in[11];
  const float* ta_b    = (const float*)d_in[12];
  const float* f_w1    = (const float*)d_in[13];
  const float* f_b1    = (const float*)d_in[14];
  const float* f_w2    = (const float*)d_in[15];
  const float* f_b2    = (const float*)d_in[16];
  const float* f_g     = (const float*)d_in[17];
  const float* f_b     = (const float*)d_in[18];

  float* out = (float*)d_out;

  // ws layout (bytes): Xb bf16 2*ME | QKVH bf16 8*ME | U fp32 4*ME | Wt bf16
  constexpr size_t EE = (size_t)Ec * Ec;           // 589824
  constexpr size_t WTOT = 3*EE + EE + 3*EE + EE + 2*(size_t)Ec*FFc;  // 9,437,184
  const size_t need = 14 * ME + 2 * WTOT;
  if (ws_size < need) return;   // clean absmax failure signals ws shortage

  short* Xb  = (short*)d_ws;
  short* Qb  = Xb + ME;
  short* Kb  = Qb + ME;
  short* Vtb = Qb + 2 * ME;     // spatial: transposed-V; temporal: normal V
  short* Hb  = Qb;              // FFN hidden reuses [1ME,5ME)
  float* U   = (float*)(Xb + 5 * ME);
  short* Wtb = (short*)(U + ME);

  short* wt_sa_qkv = Wtb;
  short* wt_sa_wo  = wt_sa_qkv + 3 * EE;
  short* wt_ta_qkv = wt_sa_wo  + EE;
  short* wt_ta_wo  = wt_ta_qkv + 3 * EE;
  short* wt_f_w1   = wt_ta_wo  + EE;
  short* wt_f_w2   = wt_f_w1   + (size_t)Ec * FFc;

  // ---- weight prep + input convert ----
  wtrans_kernel<<<dim3(12, 12, 3), 256, 0, stream>>>(sa_wqkv, wt_sa_qkv, Ec, Ec);
  wtrans_kernel<<<dim3(12, 12, 1), 256, 0, stream>>>(sa_wo,   wt_sa_wo,  Ec, Ec);
  wtrans_kernel<<<dim3(12, 12, 3), 256, 0, stream>>>(ta_wqkv, wt_ta_qkv, Ec, Ec);
  wtrans_kernel<<<dim3(12, 12, 1), 256, 0, stream>>>(ta_wo,   wt_ta_wo,  Ec, Ec);
  wtrans_kernel<<<dim3(48, 12, 1), 256, 0, stream>>>(f_w1,    wt_f_w1,   Ec, FFc);
  wtrans_kernel<<<dim3(12, 48, 1), 256, 0, stream>>>(f_w2,    wt_f_w2,   FFc, Ec);
  f2bf_kernel<<<(int)(ME / 8 / 256), 256, 0, stream>>>(x, Xb, (int)(ME / 8));

  const dim3 gQKV(Mrows / 128, Ec / 128, 3);
  const dim3 gSQ (Mrows / 128, Ec / 128, 1);
  const dim3 gFF1(Mrows / 128, FFc / 128, 1);

  // ---- Stage A: spatial attention ----
  gemm_kernel<4><<<gQKV, 256, 0, stream>>>(Xb, wt_sa_qkv, sa_bqkv, nullptr, Qb, Vtb, Mrows, Ec, Ec);
  spatial_attn_kernel<<<dim3(Bc * Sc, Hc), 256, 0, stream>>>(Qb, Kb, Vtb, Qb);
  gemm_kernel<2><<<gSQ, 256, 0, stream>>>(Qb, wt_sa_wo, sa_bo, x, U, nullptr, Mrows, Ec, Ec);
  layernorm_kernel<true><<<Mrows / 4, 256, 0, stream>>>(U, sa_g, sa_b, Xb);

  // ---- Stage B: temporal attention ----
  gemm_kernel<0><<<gQKV, 256, 0, stream>>>(Xb, wt_ta_qkv, ta_bqkv, nullptr, Qb, nullptr, Mrows, Ec, Ec);
  temporal_attn_kernel<<<Bc * Pc, 192, 0, stream>>>(Qb, Kb, Vtb, Qb);
  gemm_kernel<3><<<gSQ, 256, 0, stream>>>(Qb, wt_ta_wo, ta_bo, Xb, U, nullptr, Mrows, Ec, Ec);
  layernorm_kernel<true><<<Mrows / 4, 256, 0, stream>>>(U, ta_g, ta_b, Xb);

  // ---- Stage C: FFN ----
  gemm_kernel<1><<<gFF1, 256, 0, stream>>>(Xb, wt_f_w1, f_b1, nullptr, Hb, nullptr, Mrows, FFc, Ec);
  gemm_kernel<3><<<gSQ, 256, 0, stream>>>(Hb, wt_f_w2, f_b2, Xb, U, nullptr, Mrows, Ec, FFc);
  layernorm_kernel<false><<<Mrows / 4, 256, 0, stream>>>(U, f_g, f_b, out);
}

// Round 5
// 670.107 us; speedup vs baseline: 3.0437x; 1.1319x over previous
//
#include <hip/hip_runtime.h>
#include <hip/hip_bf16.h>
#include <math.h>

// Problem constants
constexpr int Bc = 4, Sc = 16, Pc = 256, Ec = 768, Hc = 12, HDc = 64, FFc = 3072;
constexpr int Mrows = Bc * Sc * Pc;              // 16384 token rows
constexpr size_t ME = (size_t)Mrows * Ec;        // 12,582,912 elements

typedef __attribute__((ext_vector_type(4))) float f32x4;
typedef __attribute__((ext_vector_type(8))) short s16x8;
typedef __attribute__((ext_vector_type(4))) short s16x4;

__device__ __forceinline__ short f2bf(float f) {
  union { float f; unsigned u; } v; v.f = f;
  unsigned r = (v.u + 0x7FFFu + ((v.u >> 16) & 1u)) >> 16;  // RNE
  return (short)r;
}
__device__ __forceinline__ float bf2f(short s) {
  union { unsigned u; float f; } v; v.u = ((unsigned)(unsigned short)s) << 16;
  return v.f;
}

// async global->LDS, 16B per lane; lds dest must be wave-uniform base.
__device__ __forceinline__ void async16(const void* g, void* l) {
  __builtin_amdgcn_global_load_lds(
      (const __attribute__((address_space(1))) unsigned int*)g,
      (__attribute__((address_space(3))) unsigned int*)l, 16, 0, 0);
}

// ---------------------------------------------------------------------------
// fp32 -> bf16 convert (vectorized, 8 elems/thread)
// ---------------------------------------------------------------------------
__global__ __launch_bounds__(256)
void f2bf_kernel(const float* __restrict__ in, short* __restrict__ out, int n8)
{
  int i = blockIdx.x * 256 + threadIdx.x;
  if (i >= n8) return;
  const float4* p = reinterpret_cast<const float4*>(in + (size_t)i * 8);
  float4 a = p[0], b = p[1];
  s16x8 o = { f2bf(a.x), f2bf(a.y), f2bf(a.z), f2bf(a.w),
              f2bf(b.x), f2bf(b.y), f2bf(b.z), f2bf(b.w) };
  *reinterpret_cast<s16x8*>(out + (size_t)i * 8) = o;
}

// ---------------------------------------------------------------------------
// Weight transpose-convert: W fp32 [K][N] -> Wt bf16 [N][K].
// ---------------------------------------------------------------------------
__global__ __launch_bounds__(256)
void wtrans_kernel(const float* __restrict__ Wg, short* __restrict__ Wtg,
                   int K, int N)
{
  const int z = blockIdx.z;
  const float* W  = Wg  + (size_t)z * K * N;
  short*       Wt = Wtg + (size_t)z * N * K;
  const int n0 = blockIdx.x * 64, k0 = blockIdx.y * 64;
  const int t = threadIdx.x;
  const int n  = n0 + (t >> 2);
  const int kc = k0 + (t & 3) * 16;
  short buf[16];
#pragma unroll
  for (int i = 0; i < 16; ++i)
    buf[i] = f2bf(W[(size_t)(kc + i) * N + n]);
  *reinterpret_cast<s16x8*>(&Wt[(size_t)n * K + kc])     = *reinterpret_cast<s16x8*>(&buf[0]);
  *reinterpret_cast<s16x8*>(&Wt[(size_t)n * K + kc + 8]) = *reinterpret_cast<s16x8*>(&buf[8]);
}

// ---------------------------------------------------------------------------
// GEMM (m97 structure): C = A[M,K](bf16) * Wt[z][N,K](bf16)^T + bias[z]
// 128x128 tile, 4 waves (2x2), each wave 64x64 (4x4 frags), BK=32,
// global_load_lds width-16 staging, 16x16x32 bf16 MFMA.
// OUT: 0 bf16 | 1 bf16+relu | 2 f32 + f32 residual | 3 f32 + bf16 residual
//      4 QKV-A mode: z<2 bf16 normal, z==2 writes transposed-V layout to vt
// ---------------------------------------------------------------------------
template<int OUT>
__global__ __launch_bounds__(256, 3)
void gemm_kernel(const short* __restrict__ A, const short* __restrict__ Wt,
                 const float* __restrict__ biasg, const void* __restrict__ resv,
                 void* __restrict__ Cg, short* __restrict__ vt,
                 int M, int N, int K)
{
  const int z = blockIdx.z;
  const short* Wz = Wt + (size_t)z * (size_t)N * K;
  const float* bz = biasg + (size_t)z * N;

  const int bm = blockIdx.x * 128;
  const int bn = blockIdx.y * 128;

  __shared__ short As[128 * 32];   // 8KB, linear rows of 64B
  __shared__ short Bs[128 * 32];   // 8KB

  const int tid  = threadIdx.x;
  const int lane = tid & 63;
  const int wid  = tid >> 6;
  const int wr   = wid >> 1, wc = wid & 1;
  const int l16  = lane & 15;
  const int g    = lane >> 4;
  const int srow = lane >> 2, scol = (lane & 3) * 8;  // staging: 4 lanes/row

  f32x4 acc[4][4];
#pragma unroll
  for (int m = 0; m < 4; ++m)
#pragma unroll
    for (int n = 0; n < 4; ++n) acc[m][n] = f32x4{0.f, 0.f, 0.f, 0.f};

  for (int k0 = 0; k0 < K; k0 += 32) {
#pragma unroll
    for (int is = 0; is < 2; ++is) {
      const int c = is * 4 + wid;          // chunk: 1KB = 16 rows
      const int row = c * 16 + srow;
      async16(&A[(size_t)(bm + row) * K + k0 + scol],  (char*)As + c * 1024);
      async16(&Wz[(size_t)(bn + row) * K + k0 + scol], (char*)Bs + c * 1024);
    }
    __syncthreads();

    s16x8 af[4], bf[4];
#pragma unroll
    for (int m = 0; m < 4; ++m)
      af[m] = *reinterpret_cast<const s16x8*>(
          (const char*)As + (wr * 64 + m * 16 + l16) * 64 + g * 16);
#pragma unroll
    for (int n = 0; n < 4; ++n)
      bf[n] = *reinterpret_cast<const s16x8*>(
          (const char*)Bs + (wc * 64 + n * 16 + l16) * 64 + g * 16);
#pragma unroll
    for (int m = 0; m < 4; ++m)
#pragma unroll
      for (int n = 0; n < 4; ++n)
        acc[m][n] = __builtin_amdgcn_mfma_f32_16x16x32_bf16(af[m], bf[n], acc[m][n], 0, 0, 0);
    __syncthreads();
  }

  const float* resf = (const float*)resv;
  const short* resb = (const short*)resv;
  short* Cb = (short*)Cg + (size_t)z * (size_t)M * N;
  float* Cf = (float*)Cg + (size_t)z * (size_t)M * N;

#pragma unroll
  for (int m = 0; m < 4; ++m) {
    const int row0 = bm + wr * 64 + m * 16 + g * 4;
#pragma unroll
    for (int n = 0; n < 4; ++n) {
      const int col = bn + wc * 64 + n * 16 + l16;
      if (OUT == 4 && z == 2) {
        // transposed-V: Vt[(bs*12+h)*64 + d][p], 4 consecutive p per lane
        const int bs2 = row0 >> 8, p0 = row0 & 255;
        const int h2 = col >> 6,  d2 = col & 63;
        const float bias = bz[col];
        s16x4 v = { f2bf(acc[m][n][0] + bias), f2bf(acc[m][n][1] + bias),
                    f2bf(acc[m][n][2] + bias), f2bf(acc[m][n][3] + bias) };
        *reinterpret_cast<s16x4*>(
            &vt[(((size_t)bs2 * 12 + h2) * 64 + d2) * 256 + p0]) = v;
      } else {
        const float bias = bz[col];
#pragma unroll
        for (int r = 0; r < 4; ++r) {
          float v = acc[m][n][r] + bias;
          size_t idx = (size_t)(row0 + r) * N + col;
          if (OUT == 2) v += resf[idx];
          if (OUT == 3) v += bf2f(resb[idx]);
          if (OUT == 1) v = fmaxf(v, 0.f);
          if (OUT == 2 || OUT == 3) Cf[idx] = v;
          else                      Cb[idx] = f2bf(v);
        }
      }
    }
  }
}

// ---------------------------------------------------------------------------
// Spatial attention, MFMA flash, barrier-free:
// block = (b*S+s, h, qhalf); 4 waves x 32 queries. K and V fragments read
// directly from global per lane (L1/L2-resident slabs); only P goes through
// per-wave LDS (4 KB, XOR-swizzled). No __syncthreads anywhere.
// ---------------------------------------------------------------------------
__global__ __launch_bounds__(256, 3)
void spatial_attn_kernel(const short* __restrict__ Qg, const short* __restrict__ Kg,
                         const short* __restrict__ Vt, short* __restrict__ Og)
{
  const int bs = blockIdx.x;   // 0..63
  const int h  = blockIdx.y;   // 0..11

  __shared__ short Pl[4 * 32 * 64];   // 16 KB total, per-wave 4 KB

  const int tid  = threadIdx.x;
  const int lane = tid & 63;
  const int wid  = tid >> 6;
  const int l16  = lane & 15;
  const int g    = lane >> 4;
  const int q0   = blockIdx.z * 128 + wid * 32;
  char* Pw = (char*)Pl + wid * 4096;

  const size_t rowbase = (size_t)(bs * 256) * 768 + h * 64;   // + row*768 + d
  const size_t vbase   = ((size_t)bs * 12 + h) * 64 * 256;    // Vt[d][key]

  // Q fragments (per-lane 16B global loads), held in registers
  s16x8 qa[2][2];
#pragma unroll
  for (int m = 0; m < 2; ++m)
#pragma unroll
    for (int ks = 0; ks < 2; ++ks)
      qa[m][ks] = *reinterpret_cast<const s16x8*>(
          &Qg[rowbase + (size_t)(q0 + m * 16 + l16) * 768 + ks * 32 + g * 8]);

  float mrun[2][4], lrun[2][4];
  f32x4 oac[2][4];
#pragma unroll
  for (int m = 0; m < 2; ++m)
#pragma unroll
    for (int r = 0; r < 4; ++r) { mrun[m][r] = -INFINITY; lrun[m][r] = 0.f; }
#pragma unroll
  for (int m = 0; m < 2; ++m)
#pragma unroll
    for (int n = 0; n < 4; ++n) oac[m][n] = f32x4{0.f, 0.f, 0.f, 0.f};

#pragma unroll
  for (int t = 0; t < 4; ++t) {
    const int key0 = t * 64;
    // S = Q K^T (32q x 64k per wave), K frags straight from global
    f32x4 sc[2][4];
#pragma unroll
    for (int m = 0; m < 2; ++m)
#pragma unroll
      for (int n = 0; n < 4; ++n) sc[m][n] = f32x4{0.f, 0.f, 0.f, 0.f};
#pragma unroll
    for (int ks = 0; ks < 2; ++ks) {
      s16x8 kf[4];
#pragma unroll
      for (int n = 0; n < 4; ++n) {
        const int key = key0 + n * 16 + l16;
        kf[n] = *reinterpret_cast<const s16x8*>(
            &Kg[rowbase + (size_t)key * 768 + ks * 32 + g * 8]);
      }
#pragma unroll
      for (int m = 0; m < 2; ++m)
#pragma unroll
        for (int n = 0; n < 4; ++n)
          sc[m][n] = __builtin_amdgcn_mfma_f32_16x16x32_bf16(qa[m][ks], kf[n], sc[m][n], 0, 0, 0);
    }
#pragma unroll
    for (int m = 0; m < 2; ++m)
#pragma unroll
      for (int n = 0; n < 4; ++n)
#pragma unroll
        for (int r = 0; r < 4; ++r) sc[m][n][r] *= 0.125f;

    // online softmax: q = m*16 + g*4 + r, keys across n-frags + l16 lanes
#pragma unroll
    for (int m = 0; m < 2; ++m) {
#pragma unroll
      for (int r = 0; r < 4; ++r) {
        float mx = fmaxf(fmaxf(sc[m][0][r], sc[m][1][r]), fmaxf(sc[m][2][r], sc[m][3][r]));
#pragma unroll
        for (int mk = 1; mk < 16; mk <<= 1) mx = fmaxf(mx, __shfl_xor(mx, mk, 64));
        const float mnew = fmaxf(mrun[m][r], mx);
        const float corr = __expf(mrun[m][r] - mnew);
        mrun[m][r] = mnew;
        float rs = 0.f;
#pragma unroll
        for (int n = 0; n < 4; ++n) {
          float p = __expf(sc[m][n][r] - mnew);
          sc[m][n][r] = p;
          rs += p;
        }
#pragma unroll
        for (int mk = 1; mk < 16; mk <<= 1) rs += __shfl_xor(rs, mk, 64);
        lrun[m][r] = lrun[m][r] * corr + rs;
#pragma unroll
        for (int nd = 0; nd < 4; ++nd) oac[m][nd][r] *= corr;
      }
    }
    // P -> per-wave LDS (bf16, XOR-swizzled rows of 128B)
#pragma unroll
    for (int m = 0; m < 2; ++m)
#pragma unroll
      for (int n = 0; n < 4; ++n)
#pragma unroll
        for (int r = 0; r < 4; ++r) {
          const int q = m * 16 + g * 4 + r;
          const int key = n * 16 + l16;
          const int byte = q * 128 + (((key >> 3) ^ (q & 7)) * 16) + (key & 7) * 2;
          *reinterpret_cast<short*>(Pw + byte) = f2bf(sc[m][n][r]);
        }
    // O += P V  (V frags straight from global Vt)
#pragma unroll
    for (int ks = 0; ks < 2; ++ks) {
      s16x8 pa[2], vf[4];
#pragma unroll
      for (int m = 0; m < 2; ++m) {
        const int q = m * 16 + l16;
        const int s = ks * 4 + g;
        pa[m] = *reinterpret_cast<const s16x8*>(Pw + q * 128 + ((s ^ (q & 7)) * 16));
      }
#pragma unroll
      for (int nd = 0; nd < 4; ++nd) {
        const int d = nd * 16 + l16;
        const int key = key0 + ks * 32 + g * 8;
        vf[nd] = *reinterpret_cast<const s16x8*>(&Vt[vbase + (size_t)d * 256 + key]);
      }
#pragma unroll
      for (int m = 0; m < 2; ++m)
#pragma unroll
        for (int nd = 0; nd < 4; ++nd)
          oac[m][nd] = __builtin_amdgcn_mfma_f32_16x16x32_bf16(pa[m], vf[nd], oac[m][nd], 0, 0, 0);
    }
  }

  // normalize, stage O through per-wave LDS, vectorized global write
#pragma unroll
  for (int m = 0; m < 2; ++m)
#pragma unroll
    for (int r = 0; r < 4; ++r) {
      const float inv = 1.f / lrun[m][r];
#pragma unroll
      for (int nd = 0; nd < 4; ++nd) oac[m][nd][r] *= inv;
    }
#pragma unroll
  for (int m = 0; m < 2; ++m)
#pragma unroll
    for (int nd = 0; nd < 4; ++nd)
#pragma unroll
      for (int r = 0; r < 4; ++r) {
        const int q = m * 16 + g * 4 + r;
        const int d = nd * 16 + l16;
        const int byte = q * 128 + (((d >> 3) ^ (q & 7)) * 16) + (d & 7) * 2;
        *reinterpret_cast<short*>(Pw + byte) = f2bf(oac[m][nd][r]);
      }
#pragma unroll
  for (int it = 0; it < 4; ++it) {
    const int slot = it * 64 + lane;          // 0..255 -> 32q x 4 slots
    const int q = slot >> 3, sl = slot & 7;
    const int d0 = (sl ^ (q & 7)) * 8;
    s16x8 v = *reinterpret_cast<const s16x8*>(Pw + slot * 16);
    *reinterpret_cast<s16x8*>(
        &Og[rowbase + (size_t)(q0 + q) * 768 + d0]) = v;
  }
}

// ---------------------------------------------------------------------------
// Temporal attention (causal over S=16): per (b,p) block, thread=(h,i).
// ---------------------------------------------------------------------------
__global__ __launch_bounds__(192)
void temporal_attn_kernel(const short* __restrict__ Qg, const short* __restrict__ Kg,
                          const short* __restrict__ Vg, short* __restrict__ Og)
{
  const int bp = blockIdx.x;
  const int b = bp >> 8, p = bp & 255;
  const int tid = threadIdx.x;
  const int h = tid >> 4, i = tid & 15;

  const float scale = 0.125f;
  auto rowoff = [&](int s) {
    return ((size_t)(b * Sc + s) * Pc + p) * Ec + (size_t)h * HDc;
  };

  float q[HDc];
  {
    const short* qp = &Qg[rowoff(i)];
#pragma unroll
    for (int c = 0; c < 8; ++c) {
      s16x8 v = *reinterpret_cast<const s16x8*>(qp + c * 8);
#pragma unroll
      for (int e = 0; e < 8; ++e) q[c * 8 + e] = bf2f(v[e]) * scale;
    }
  }
  float m = -INFINITY, l = 0.f;
  float o[HDc];
#pragma unroll
  for (int d = 0; d < HDc; ++d) o[d] = 0.f;

  for (int j = 0; j <= i; ++j) {
    const short* kp = &Kg[rowoff(j)];
    float s = 0.f;
#pragma unroll
    for (int c = 0; c < 8; ++c) {
      s16x8 kv = *reinterpret_cast<const s16x8*>(kp + c * 8);
#pragma unroll
      for (int e = 0; e < 8; ++e) s += q[c * 8 + e] * bf2f(kv[e]);
    }
    float mn   = fmaxf(m, s);
    float corr = __expf(m - mn);
    float pw   = __expf(s - mn);
    l = l * corr + pw;
    const short* vp = &Vg[rowoff(j)];
#pragma unroll
    for (int c = 0; c < 8; ++c) {
      s16x8 vv = *reinterpret_cast<const s16x8*>(vp + c * 8);
#pragma unroll
      for (int e = 0; e < 8; ++e)
        o[c * 8 + e] = fmaf(pw, bf2f(vv[e]), o[c * 8 + e] * corr);
    }
    m = mn;
  }
  const float inv = 1.f / l;
  short* op = &Og[rowoff(i)];
#pragma unroll
  for (int c = 0; c < 8; ++c) {
    s16x8 v;
#pragma unroll
    for (int e = 0; e < 8; ++e) v[e] = f2bf(o[c * 8 + e] * inv);
    *reinterpret_cast<s16x8*>(op + c * 8) = v;
  }
}

// ---------------------------------------------------------------------------
// LayerNorm over E=768: one wave per row, 4 rows per block.
// ---------------------------------------------------------------------------
template<bool OUTBF>
__global__ __launch_bounds__(256)
void layernorm_kernel(const float* __restrict__ U, const float* __restrict__ g,
                      const float* __restrict__ be, void* __restrict__ outv)
{
  const int tid  = threadIdx.x;
  const int lane = tid & 63, w = tid >> 6;
  const size_t row = (size_t)blockIdx.x * 4 + w;
  const float* u = U + row * Ec;

  float x[12];
#pragma unroll
  for (int c = 0; c < 3; ++c) {
    float4 v = *reinterpret_cast<const float4*>(&u[c * 256 + lane * 4]);
    x[c*4+0] = v.x; x[c*4+1] = v.y; x[c*4+2] = v.z; x[c*4+3] = v.w;
  }
  float s = 0.f;
#pragma unroll
  for (int k = 0; k < 12; ++k) s += x[k];
#pragma unroll
  for (int off = 32; off > 0; off >>= 1) s += __shfl_xor(s, off, 64);
  const float mean = s * (1.f / 768.f);

  float vs = 0.f;
#pragma unroll
  for (int k = 0; k < 12; ++k) { float d = x[k] - mean; vs += d * d; }
#pragma unroll
  for (int off = 32; off > 0; off >>= 1) vs += __shfl_xor(vs, off, 64);
  const float rs = rsqrtf(vs * (1.f / 768.f) + 1e-5f);

#pragma unroll
  for (int c = 0; c < 3; ++c) {
    int idx = c * 256 + lane * 4;
    float4 gv = *reinterpret_cast<const float4*>(&g[idx]);
    float4 bv = *reinterpret_cast<const float4*>(&be[idx]);
    float r0 = (x[c*4+0] - mean) * rs * gv.x + bv.x;
    float r1 = (x[c*4+1] - mean) * rs * gv.y + bv.y;
    float r2 = (x[c*4+2] - mean) * rs * gv.z + bv.z;
    float r3 = (x[c*4+3] - mean) * rs * gv.w + bv.w;
    if (OUTBF) {
      short* op = (short*)outv + row * Ec + idx;
      s16x4 v = { f2bf(r0), f2bf(r1), f2bf(r2), f2bf(r3) };
      *reinterpret_cast<s16x4*>(op) = v;
    } else {
      float* op = (float*)outv + row * Ec + idx;
      *reinterpret_cast<float4*>(op) = make_float4(r0, r1, r2, r3);
    }
  }
}

// ---------------------------------------------------------------------------
extern "C" void kernel_launch(void* const* d_in, const int* in_sizes, int n_in,
                              void* d_out, int out_size, void* d_ws, size_t ws_size,
                              hipStream_t stream)
{
  const float* x       = (const float*)d_in[0];
  const float* sa_wqkv = (const float*)d_in[1];
  const float* sa_bqkv = (const float*)d_in[2];
  const float* sa_wo   = (const float*)d_in[3];
  const float* sa_bo   = (const float*)d_in[4];
  const float* sa_g    = (const float*)d_in[5];
  const float* sa_b    = (const float*)d_in[6];
  const float* ta_wqkv = (const float*)d_in[7];
  const float* ta_bqkv = (const float*)d_in[8];
  const float* ta_wo   = (const float*)d_in[9];
  const float* ta_bo   = (const float*)d_in[10];
  const float* ta_g    = (const float*)d_in[11];
  const float* ta_b    = (const float*)d_in[12];
  const float* f_w1    = (const float*)d_in[13];
  const float* f_b1    = (const float*)d_in[14];
  const float* f_w2    = (const float*)d_in[15];
  const float* f_b2    = (const float*)d_in[16];
  const float* f_g     = (const float*)d_in[17];
  const float* f_b     = (const float*)d_in[18];

  float* out = (float*)d_out;

  // ws layout (bytes): Xb bf16 2*ME | QKVH bf16 8*ME | U fp32 4*ME | Wt bf16
  constexpr size_t EE = (size_t)Ec * Ec;           // 589824
  constexpr size_t WTOT = 3*EE + EE + 3*EE + EE + 2*(size_t)Ec*FFc;  // 9,437,184
  const size_t need = 14 * ME + 2 * WTOT;
  if (ws_size < need) return;   // clean absmax failure signals ws shortage

  short* Xb  = (short*)d_ws;
  short* Qb  = Xb + ME;
  short* Kb  = Qb + ME;
  short* Vtb = Qb + 2 * ME;     // spatial: transposed-V; temporal: normal V
  short* Hb  = Qb;              // FFN hidden reuses [1ME,5ME)
  float* U   = (float*)(Xb + 5 * ME);
  short* Wtb = (short*)(U + ME);

  short* wt_sa_qkv = Wtb;
  short* wt_sa_wo  = wt_sa_qkv + 3 * EE;
  short* wt_ta_qkv = wt_sa_wo  + EE;
  short* wt_ta_wo  = wt_ta_qkv + 3 * EE;
  short* wt_f_w1   = wt_ta_wo  + EE;
  short* wt_f_w2   = wt_f_w1   + (size_t)Ec * FFc;

  // ---- weight prep + input convert ----
  wtrans_kernel<<<dim3(12, 12, 3), 256, 0, stream>>>(sa_wqkv, wt_sa_qkv, Ec, Ec);
  wtrans_kernel<<<dim3(12, 12, 1), 256, 0, stream>>>(sa_wo,   wt_sa_wo,  Ec, Ec);
  wtrans_kernel<<<dim3(12, 12, 3), 256, 0, stream>>>(ta_wqkv, wt_ta_qkv, Ec, Ec);
  wtrans_kernel<<<dim3(12, 12, 1), 256, 0, stream>>>(ta_wo,   wt_ta_wo,  Ec, Ec);
  wtrans_kernel<<<dim3(48, 12, 1), 256, 0, stream>>>(f_w1,    wt_f_w1,   Ec, FFc);
  wtrans_kernel<<<dim3(12, 48, 1), 256, 0, stream>>>(f_w2,    wt_f_w2,   FFc, Ec);
  f2bf_kernel<<<(int)(ME / 8 / 256), 256, 0, stream>>>(x, Xb, (int)(ME / 8));

  const dim3 gQKV(Mrows / 128, Ec / 128, 3);
  const dim3 gSQ (Mrows / 128, Ec / 128, 1);
  const dim3 gFF1(Mrows / 128, FFc / 128, 1);

  // ---- Stage A: spatial attention ----
  gemm_kernel<4><<<gQKV, 256, 0, stream>>>(Xb, wt_sa_qkv, sa_bqkv, nullptr, Qb, Vtb, Mrows, Ec, Ec);
  spatial_attn_kernel<<<dim3(Bc * Sc, Hc, 2), 256, 0, stream>>>(Qb, Kb, Vtb, Qb);
  gemm_kernel<2><<<gSQ, 256, 0, stream>>>(Qb, wt_sa_wo, sa_bo, x, U, nullptr, Mrows, Ec, Ec);
  layernorm_kernel<true><<<Mrows / 4, 256, 0, stream>>>(U, sa_g, sa_b, Xb);

  // ---- Stage B: temporal attention ----
  gemm_kernel<0><<<gQKV, 256, 0, stream>>>(Xb, wt_ta_qkv, ta_bqkv, nullptr, Qb, nullptr, Mrows, Ec, Ec);
  temporal_attn_kernel<<<Bc * Pc, 192, 0, stream>>>(Qb, Kb, Vtb, Qb);
  gemm_kernel<3><<<gSQ, 256, 0, stream>>>(Qb, wt_ta_wo, ta_bo, Xb, U, nullptr, Mrows, Ec, Ec);
  layernorm_kernel<true><<<Mrows / 4, 256, 0, stream>>>(U, ta_g, ta_b, Xb);

  // ---- Stage C: FFN ----
  gemm_kernel<1><<<gFF1, 256, 0, stream>>>(Xb, wt_f_w1, f_b1, nullptr, Hb, nullptr, Mrows, FFc, Ec);
  gemm_kernel<3><<<gSQ, 256, 0, stream>>>(Hb, wt_f_w2, f_b2, Xb, U, nullptr, Mrows, Ec, FFc);
  layernorm_kernel<false><<<Mrows / 4, 256, 0, stream>>>(U, f_g, f_b, out);
}

// Round 6
// 643.221 us; speedup vs baseline: 3.1709x; 1.0418x over previous
//
#include <hip/hip_runtime.h>
#include <hip/hip_bf16.h>
#include <math.h>

// Problem constants
constexpr int Bc = 4, Sc = 16, Pc = 256, Ec = 768, Hc = 12, HDc = 64, FFc = 3072;
constexpr int Mrows = Bc * Sc * Pc;              // 16384 token rows
constexpr size_t ME = (size_t)Mrows * Ec;        // 12,582,912 elements

typedef __attribute__((ext_vector_type(4))) float f32x4;
typedef __attribute__((ext_vector_type(8))) short s16x8;
typedef __attribute__((ext_vector_type(4))) short s16x4;

__device__ __forceinline__ short f2bf(float f) {
  union { float f; unsigned u; } v; v.f = f;
  unsigned r = (v.u + 0x7FFFu + ((v.u >> 16) & 1u)) >> 16;  // RNE
  return (short)r;
}
__device__ __forceinline__ float bf2f(short s) {
  union { unsigned u; float f; } v; v.u = ((unsigned)(unsigned short)s) << 16;
  return v.f;
}

// async global->LDS, 16B per lane; lds dest must be wave-uniform base.
__device__ __forceinline__ void async16(const void* g, void* l) {
  __builtin_amdgcn_global_load_lds(
      (const __attribute__((address_space(1))) unsigned int*)g,
      (__attribute__((address_space(3))) unsigned int*)l, 16, 0, 0);
}

// ---------------------------------------------------------------------------
// fp32 -> bf16 convert (vectorized, 8 elems/thread)
// ---------------------------------------------------------------------------
__global__ __launch_bounds__(256)
void f2bf_kernel(const float* __restrict__ in, short* __restrict__ out, int n8)
{
  int i = blockIdx.x * 256 + threadIdx.x;
  if (i >= n8) return;
  const float4* p = reinterpret_cast<const float4*>(in + (size_t)i * 8);
  float4 a = p[0], b = p[1];
  s16x8 o = { f2bf(a.x), f2bf(a.y), f2bf(a.z), f2bf(a.w),
              f2bf(b.x), f2bf(b.y), f2bf(b.z), f2bf(b.w) };
  *reinterpret_cast<s16x8*>(out + (size_t)i * 8) = o;
}

// ---------------------------------------------------------------------------
// Weight transpose-convert: W fp32 [K][N] -> Wt bf16 [N][K].
// ---------------------------------------------------------------------------
__global__ __launch_bounds__(256)
void wtrans_kernel(const float* __restrict__ Wg, short* __restrict__ Wtg,
                   int K, int N)
{
  const int z = blockIdx.z;
  const float* W  = Wg  + (size_t)z * K * N;
  short*       Wt = Wtg + (size_t)z * N * K;
  const int n0 = blockIdx.x * 64, k0 = blockIdx.y * 64;
  const int t = threadIdx.x;
  const int n  = n0 + (t >> 2);
  const int kc = k0 + (t & 3) * 16;
  short buf[16];
#pragma unroll
  for (int i = 0; i < 16; ++i)
    buf[i] = f2bf(W[(size_t)(kc + i) * N + n]);
  *reinterpret_cast<s16x8*>(&Wt[(size_t)n * K + kc])     = *reinterpret_cast<s16x8*>(&buf[0]);
  *reinterpret_cast<s16x8*>(&Wt[(size_t)n * K + kc + 8]) = *reinterpret_cast<s16x8*>(&buf[8]);
}

// ---------------------------------------------------------------------------
// GEMM, 8-phase 256x256 template (T1+T2+T3+T4+T5):
// C = A[M,K](bf16) * Wt[z][N,K](bf16)^T + bias[z]
// 512 threads = 8 waves (2M x 4N); per-wave 128x64 (acc[8][4]); BK=64;
// LDS 128KB = 2 slots x (A 32K | B 32K), rows of 128B, XOR-16B swizzle;
// 8 phases per iter (2 K-tiles), counted vmcnt(4) at phases 4/8 only.
// OUT: 0 bf16 | 1 bf16+relu | 2 f32 + f32 residual | 3 f32 + bf16 residual
//      4 QKV-A mode: z<2 bf16 normal, z==2 writes transposed-V layout to vt
// ---------------------------------------------------------------------------
#define LDFRAG(base, row, kc) \
  (*reinterpret_cast<const s16x8*>((base) + (row) * 128 + ((((kc) ^ ((row) & 7)) << 4))))

#define PH_READS(Aslot, Bslot, q, LDB) \
  do { \
    if (LDB) { \
      _Pragma("unroll") \
      for (int nj = 0; nj < 4; ++nj) { \
        bfr[nj][0] = LDFRAG((Bslot), wc * 64 + nj * 16 + l16, g); \
        bfr[nj][1] = LDFRAG((Bslot), wc * 64 + nj * 16 + l16, 4 + g); \
      } \
    } \
    _Pragma("unroll") \
    for (int mi = 0; mi < 2; ++mi) { \
      afr[mi][0] = LDFRAG((Aslot), wr * 128 + ((q) * 2 + mi) * 16 + l16, g); \
      afr[mi][1] = LDFRAG((Aslot), wr * 128 + ((q) * 2 + mi) * 16 + l16, 4 + g); \
    } \
  } while (0)

#define PH_SYNC_MMA(q) \
  do { \
    __builtin_amdgcn_sched_barrier(0); \
    __builtin_amdgcn_s_barrier(); \
    asm volatile("s_waitcnt lgkmcnt(0)" ::: "memory"); \
    __builtin_amdgcn_sched_barrier(0); \
    __builtin_amdgcn_s_setprio(1); \
    _Pragma("unroll") \
    for (int mi = 0; mi < 2; ++mi) \
      _Pragma("unroll") \
      for (int nj = 0; nj < 4; ++nj) { \
        acc[(q) * 2 + mi][nj] = __builtin_amdgcn_mfma_f32_16x16x32_bf16( \
            afr[mi][0], bfr[nj][0], acc[(q) * 2 + mi][nj], 0, 0, 0); \
        acc[(q) * 2 + mi][nj] = __builtin_amdgcn_mfma_f32_16x16x32_bf16( \
            afr[mi][1], bfr[nj][1], acc[(q) * 2 + mi][nj], 0, 0, 0); \
      } \
    __builtin_amdgcn_s_setprio(0); \
  } while (0)

#define PH_END \
  do { __builtin_amdgcn_s_barrier(); __builtin_amdgcn_sched_barrier(0); } while (0)

#define PH_END_VM \
  do { \
    asm volatile("s_waitcnt vmcnt(4)" ::: "memory"); \
    __builtin_amdgcn_sched_barrier(0); \
    __builtin_amdgcn_s_barrier(); \
    __builtin_amdgcn_sched_barrier(0); \
  } while (0)

template<int OUT>
__global__ __launch_bounds__(512, 2)
void gemm256_kernel(const short* __restrict__ A, const short* __restrict__ Wt,
                    const float* __restrict__ biasg, const void* __restrict__ resv,
                    void* __restrict__ Cg, short* __restrict__ vt,
                    int M, int N, int K)
{
  __shared__ char smem[131072];
  const int z = blockIdx.z;
  const short* __restrict__ Wz = Wt + (size_t)z * (size_t)N * K;
  const float* __restrict__ bz = biasg + (size_t)z * N;

  // T1: bijective XCD swizzle (all grids are multiples of 8)
  const int nwg = gridDim.x;
  const int swz = ((int)blockIdx.x & 7) * (nwg >> 3) + ((int)blockIdx.x >> 3);
  const int NT = N >> 8;
  const int bm = (swz / NT) << 8;
  const int bn = (swz % NT) << 8;

  const int tid  = threadIdx.x;
  const int lane = tid & 63;
  const int wid  = tid >> 6;
  const int wr   = wid >> 2;        // 0..1
  const int wc   = wid & 3;         // 0..3
  const int l16  = lane & 15;
  const int g    = lane >> 4;

  char* const As0 = smem;
  char* const Bs0 = smem + 32768;
  char* const As1 = smem + 65536;
  char* const Bs1 = smem + 98304;

  // staging constants: lane covers (row = lane>>3, chunk = lane&7) of a 1KB
  // wave region; source chunk inverse-swizzled so LDS-linear + swizzled read
  // is consistent (rule #21).
  const int srow = lane >> 3;
  const int scol = ((lane & 7) ^ srow) * 8;
  const int ldso = wid * 1024;

  auto stageG = [&](const short* __restrict__ G, int grow0, int k0, char* ldsHalf) {
    const size_t r0 = (size_t)(grow0 + wid * 8 + srow);
    async16(G + r0 * K + (k0 + scol), ldsHalf + ldso);
    async16(G + (r0 + 64) * K + (k0 + scol), ldsHalf + 8192 + ldso);
  };

  f32x4 acc[8][4];
  s16x8 bfr[4][2];
  s16x8 afr[2][2];
#pragma unroll
  for (int mi = 0; mi < 8; ++mi)
#pragma unroll
    for (int nj = 0; nj < 4; ++nj) acc[mi][nj] = f32x4{0.f, 0.f, 0.f, 0.f};

  const int ntile = K >> 6;
  const int nit   = ntile >> 1;

  // prologue: tile0 A+B -> slot0, tile1 B -> slot1 (A(t1) staged in ph1-2)
  stageG(A,  bm,        0,  As0);
  stageG(A,  bm + 128,  0,  As0 + 16384);
  stageG(Wz, bn,        0,  Bs0);
  stageG(Wz, bn + 128,  0,  Bs0 + 16384);
  stageG(Wz, bn,        64, Bs1);
  stageG(Wz, bn + 128,  64, Bs1 + 16384);
  asm volatile("s_waitcnt vmcnt(4)" ::: "memory");
  __builtin_amdgcn_sched_barrier(0);
  __builtin_amdgcn_s_barrier();

  for (int j = 0; j < nit; ++j) {
    const int t1k = (2 * j + 1) << 6;
    const int t2k = (2 * j + 2) << 6;
    const int t3k = (2 * j + 3) << 6;
    const bool s2 = (2 * j + 2) < ntile;
    const bool s3 = (2 * j + 3) < ntile;

    // ---- K-tile 2j (slot0), phases 1-4 ----
    PH_READS(As0, Bs0, 0, true);
    stageG(A, bm, t1k, As1);                       // A(t1) h0 -> slot1
    PH_SYNC_MMA(0);
    PH_END;

    PH_READS(As0, Bs0, 1, false);
    stageG(A, bm + 128, t1k, As1 + 16384);         // A(t1) h1
    PH_SYNC_MMA(1);
    PH_END;

    PH_READS(As0, Bs0, 2, false);
    if (s2) stageG(Wz, bn, t2k, Bs0);              // B(t2) h0 (Bs0 free since ph1)
    PH_SYNC_MMA(2);
    PH_END;

    PH_READS(As0, Bs0, 3, false);
    if (s2) stageG(Wz, bn + 128, t2k, Bs0 + 16384);// B(t2) h1
    PH_SYNC_MMA(3);
    PH_END_VM;                                     // forces A(t1), B(t1) landed

    // ---- K-tile 2j+1 (slot1), phases 5-8 ----
    PH_READS(As1, Bs1, 0, true);
    if (s2) stageG(A, bm, t2k, As0);               // A(t2) h0 (As0 free since ph4)
    PH_SYNC_MMA(0);
    PH_END;

    PH_READS(As1, Bs1, 1, false);
    if (s2) stageG(A, bm + 128, t2k, As0 + 16384); // A(t2) h1
    PH_SYNC_MMA(1);
    PH_END;

    PH_READS(As1, Bs1, 2, false);
    if (s3) stageG(Wz, bn, t3k, Bs1);              // B(t3) h0 (Bs1 free since ph5)
    PH_SYNC_MMA(2);
    PH_END;

    PH_READS(As1, Bs1, 3, false);
    if (s3) stageG(Wz, bn + 128, t3k, Bs1 + 16384);// B(t3) h1
    PH_SYNC_MMA(3);
    PH_END_VM;                                     // forces B(t2), A(t2) landed
  }

  const float* resf = (const float*)resv;
  const short* resb = (const short*)resv;
  short* Cb = (short*)Cg + (size_t)z * (size_t)M * N;
  float* Cf = (float*)Cg + (size_t)z * (size_t)M * N;

#pragma unroll
  for (int mi = 0; mi < 8; ++mi) {
    const int row0 = bm + wr * 128 + mi * 16 + g * 4;
#pragma unroll
    for (int nj = 0; nj < 4; ++nj) {
      const int col = bn + wc * 64 + nj * 16 + l16;
      if (OUT == 4 && z == 2) {
        // transposed-V: Vt[(bs*12+h)*64 + d][p], 4 consecutive p per lane
        const int bs2 = row0 >> 8, p0 = row0 & 255;
        const int h2 = col >> 6,  d2 = col & 63;
        const float bias = bz[col];
        s16x4 v = { f2bf(acc[mi][nj][0] + bias), f2bf(acc[mi][nj][1] + bias),
                    f2bf(acc[mi][nj][2] + bias), f2bf(acc[mi][nj][3] + bias) };
        *reinterpret_cast<s16x4*>(
            &vt[(((size_t)bs2 * 12 + h2) * 64 + d2) * 256 + p0]) = v;
      } else {
        const float bias = bz[col];
#pragma unroll
        for (int r = 0; r < 4; ++r) {
          float v = acc[mi][nj][r] + bias;
          size_t idx = (size_t)(row0 + r) * N + col;
          if (OUT == 2) v += resf[idx];
          if (OUT == 3) v += bf2f(resb[idx]);
          if (OUT == 1) v = fmaxf(v, 0.f);
          if (OUT == 2 || OUT == 3) Cf[idx] = v;
          else                      Cb[idx] = f2bf(v);
        }
      }
    }
  }
}

// ---------------------------------------------------------------------------
// Spatial attention, MFMA flash, barrier-free:
// block = (b*S+s, h, qhalf); 4 waves x 32 queries. K and V fragments read
// directly from global per lane (L1/L2-resident slabs); only P goes through
// per-wave LDS (4 KB, XOR-swizzled). No __syncthreads anywhere.
// ---------------------------------------------------------------------------
__global__ __launch_bounds__(256, 3)
void spatial_attn_kernel(const short* __restrict__ Qg, const short* __restrict__ Kg,
                         const short* __restrict__ Vt, short* __restrict__ Og)
{
  const int bs = blockIdx.x;   // 0..63
  const int h  = blockIdx.y;   // 0..11

  __shared__ short Pl[4 * 32 * 64];   // 16 KB total, per-wave 4 KB

  const int tid  = threadIdx.x;
  const int lane = tid & 63;
  const int wid  = tid >> 6;
  const int l16  = lane & 15;
  const int g    = lane >> 4;
  const int q0   = blockIdx.z * 128 + wid * 32;
  char* Pw = (char*)Pl + wid * 4096;

  const size_t rowbase = (size_t)(bs * 256) * 768 + h * 64;   // + row*768 + d
  const size_t vbase   = ((size_t)bs * 12 + h) * 64 * 256;    // Vt[d][key]

  // Q fragments (per-lane 16B global loads), held in registers
  s16x8 qa[2][2];
#pragma unroll
  for (int m = 0; m < 2; ++m)
#pragma unroll
    for (int ks = 0; ks < 2; ++ks)
      qa[m][ks] = *reinterpret_cast<const s16x8*>(
          &Qg[rowbase + (size_t)(q0 + m * 16 + l16) * 768 + ks * 32 + g * 8]);

  float mrun[2][4], lrun[2][4];
  f32x4 oac[2][4];
#pragma unroll
  for (int m = 0; m < 2; ++m)
#pragma unroll
    for (int r = 0; r < 4; ++r) { mrun[m][r] = -INFINITY; lrun[m][r] = 0.f; }
#pragma unroll
  for (int m = 0; m < 2; ++m)
#pragma unroll
    for (int n = 0; n < 4; ++n) oac[m][n] = f32x4{0.f, 0.f, 0.f, 0.f};

#pragma unroll
  for (int t = 0; t < 4; ++t) {
    const int key0 = t * 64;
    // S = Q K^T (32q x 64k per wave), K frags straight from global
    f32x4 sc[2][4];
#pragma unroll
    for (int m = 0; m < 2; ++m)
#pragma unroll
      for (int n = 0; n < 4; ++n) sc[m][n] = f32x4{0.f, 0.f, 0.f, 0.f};
#pragma unroll
    for (int ks = 0; ks < 2; ++ks) {
      s16x8 kf[4];
#pragma unroll
      for (int n = 0; n < 4; ++n) {
        const int key = key0 + n * 16 + l16;
        kf[n] = *reinterpret_cast<const s16x8*>(
            &Kg[rowbase + (size_t)key * 768 + ks * 32 + g * 8]);
      }
#pragma unroll
      for (int m = 0; m < 2; ++m)
#pragma unroll
        for (int n = 0; n < 4; ++n)
          sc[m][n] = __builtin_amdgcn_mfma_f32_16x16x32_bf16(qa[m][ks], kf[n], sc[m][n], 0, 0, 0);
    }
#pragma unroll
    for (int m = 0; m < 2; ++m)
#pragma unroll
      for (int n = 0; n < 4; ++n)
#pragma unroll
        for (int r = 0; r < 4; ++r) sc[m][n][r] *= 0.125f;

    // online softmax: q = m*16 + g*4 + r, keys across n-frags + l16 lanes
#pragma unroll
    for (int m = 0; m < 2; ++m) {
#pragma unroll
      for (int r = 0; r < 4; ++r) {
        float mx = fmaxf(fmaxf(sc[m][0][r], sc[m][1][r]), fmaxf(sc[m][2][r], sc[m][3][r]));
#pragma unroll
        for (int mk = 1; mk < 16; mk <<= 1) mx = fmaxf(mx, __shfl_xor(mx, mk, 64));
        const float mnew = fmaxf(mrun[m][r], mx);
        const float corr = __expf(mrun[m][r] - mnew);
        mrun[m][r] = mnew;
        float rs = 0.f;
#pragma unroll
        for (int n = 0; n < 4; ++n) {
          float p = __expf(sc[m][n][r] - mnew);
          sc[m][n][r] = p;
          rs += p;
        }
#pragma unroll
        for (int mk = 1; mk < 16; mk <<= 1) rs += __shfl_xor(rs, mk, 64);
        lrun[m][r] = lrun[m][r] * corr + rs;
#pragma unroll
        for (int nd = 0; nd < 4; ++nd) oac[m][nd][r] *= corr;
      }
    }
    // P -> per-wave LDS (bf16, XOR-swizzled rows of 128B)
#pragma unroll
    for (int m = 0; m < 2; ++m)
#pragma unroll
      for (int n = 0; n < 4; ++n)
#pragma unroll
        for (int r = 0; r < 4; ++r) {
          const int q = m * 16 + g * 4 + r;
          const int key = n * 16 + l16;
          const int byte = q * 128 + (((key >> 3) ^ (q & 7)) * 16) + (key & 7) * 2;
          *reinterpret_cast<short*>(Pw + byte) = f2bf(sc[m][n][r]);
        }
    // O += P V  (V frags straight from global Vt)
#pragma unroll
    for (int ks = 0; ks < 2; ++ks) {
      s16x8 pa[2], vf[4];
#pragma unroll
      for (int m = 0; m < 2; ++m) {
        const int q = m * 16 + l16;
        const int s = ks * 4 + g;
        pa[m] = *reinterpret_cast<const s16x8*>(Pw + q * 128 + ((s ^ (q & 7)) * 16));
      }
#pragma unroll
      for (int nd = 0; nd < 4; ++nd) {
        const int d = nd * 16 + l16;
        const int key = key0 + ks * 32 + g * 8;
        vf[nd] = *reinterpret_cast<const s16x8*>(&Vt[vbase + (size_t)d * 256 + key]);
      }
#pragma unroll
      for (int m = 0; m < 2; ++m)
#pragma unroll
        for (int nd = 0; nd < 4; ++nd)
          oac[m][nd] = __builtin_amdgcn_mfma_f32_16x16x32_bf16(pa[m], vf[nd], oac[m][nd], 0, 0, 0);
    }
  }

  // normalize, stage O through per-wave LDS, vectorized global write
#pragma unroll
  for (int m = 0; m < 2; ++m)
#pragma unroll
    for (int r = 0; r < 4; ++r) {
      const float inv = 1.f / lrun[m][r];
#pragma unroll
      for (int nd = 0; nd < 4; ++nd) oac[m][nd][r] *= inv;
    }
#pragma unroll
  for (int m = 0; m < 2; ++m)
#pragma unroll
    for (int nd = 0; nd < 4; ++nd)
#pragma unroll
      for (int r = 0; r < 4; ++r) {
        const int q = m * 16 + g * 4 + r;
        const int d = nd * 16 + l16;
        const int byte = q * 128 + (((d >> 3) ^ (q & 7)) * 16) + (d & 7) * 2;
        *reinterpret_cast<short*>(Pw + byte) = f2bf(oac[m][nd][r]);
      }
#pragma unroll
  for (int it = 0; it < 4; ++it) {
    const int slot = it * 64 + lane;          // 0..255 -> 32q x 4 slots
    const int q = slot >> 3, sl = slot & 7;
    const int d0 = (sl ^ (q & 7)) * 8;
    s16x8 v = *reinterpret_cast<const s16x8*>(Pw + slot * 16);
    *reinterpret_cast<s16x8*>(
        &Og[rowbase + (size_t)(q0 + q) * 768 + d0]) = v;
  }
}

// ---------------------------------------------------------------------------
// Temporal attention (causal over S=16): per (b,p) block, thread=(h,i).
// ---------------------------------------------------------------------------
__global__ __launch_bounds__(192)
void temporal_attn_kernel(const short* __restrict__ Qg, const short* __restrict__ Kg,
                          const short* __restrict__ Vg, short* __restrict__ Og)
{
  const int bp = blockIdx.x;
  const int b = bp >> 8, p = bp & 255;
  const int tid = threadIdx.x;
  const int h = tid >> 4, i = tid & 15;

  const float scale = 0.125f;
  auto rowoff = [&](int s) {
    return ((size_t)(b * Sc + s) * Pc + p) * Ec + (size_t)h * HDc;
  };

  float q[HDc];
  {
    const short* qp = &Qg[rowoff(i)];
#pragma unroll
    for (int c = 0; c < 8; ++c) {
      s16x8 v = *reinterpret_cast<const s16x8*>(qp + c * 8);
#pragma unroll
      for (int e = 0; e < 8; ++e) q[c * 8 + e] = bf2f(v[e]) * scale;
    }
  }
  float m = -INFINITY, l = 0.f;
  float o[HDc];
#pragma unroll
  for (int d = 0; d < HDc; ++d) o[d] = 0.f;

  for (int j = 0; j <= i; ++j) {
    const short* kp = &Kg[rowoff(j)];
    float s = 0.f;
#pragma unroll
    for (int c = 0; c < 8; ++c) {
      s16x8 kv = *reinterpret_cast<const s16x8*>(kp + c * 8);
#pragma unroll
      for (int e = 0; e < 8; ++e) s += q[c * 8 + e] * bf2f(kv[e]);
    }
    float mn   = fmaxf(m, s);
    float corr = __expf(m - mn);
    float pw   = __expf(s - mn);
    l = l * corr + pw;
    const short* vp = &Vg[rowoff(j)];
#pragma unroll
    for (int c = 0; c < 8; ++c) {
      s16x8 vv = *reinterpret_cast<const s16x8*>(vp + c * 8);
#pragma unroll
      for (int e = 0; e < 8; ++e)
        o[c * 8 + e] = fmaf(pw, bf2f(vv[e]), o[c * 8 + e] * corr);
    }
    m = mn;
  }
  const float inv = 1.f / l;
  short* op = &Og[rowoff(i)];
#pragma unroll
  for (int c = 0; c < 8; ++c) {
    s16x8 v;
#pragma unroll
    for (int e = 0; e < 8; ++e) v[e] = f2bf(o[c * 8 + e] * inv);
    *reinterpret_cast<s16x8*>(op + c * 8) = v;
  }
}

// ---------------------------------------------------------------------------
// LayerNorm over E=768: one wave per row, 4 rows per block.
// ---------------------------------------------------------------------------
template<bool OUTBF>
__global__ __launch_bounds__(256)
void layernorm_kernel(const float* __restrict__ U, const float* __restrict__ g,
                      const float* __restrict__ be, void* __restrict__ outv)
{
  const int tid  = threadIdx.x;
  const int lane = tid & 63, w = tid >> 6;
  const size_t row = (size_t)blockIdx.x * 4 + w;
  const float* u = U + row * Ec;

  float x[12];
#pragma unroll
  for (int c = 0; c < 3; ++c) {
    float4 v = *reinterpret_cast<const float4*>(&u[c * 256 + lane * 4]);
    x[c*4+0] = v.x; x[c*4+1] = v.y; x[c*4+2] = v.z; x[c*4+3] = v.w;
  }
  float s = 0.f;
#pragma unroll
  for (int k = 0; k < 12; ++k) s += x[k];
#pragma unroll
  for (int off = 32; off > 0; off >>= 1) s += __shfl_xor(s, off, 64);
  const float mean = s * (1.f / 768.f);

  float vs = 0.f;
#pragma unroll
  for (int k = 0; k < 12; ++k) { float d = x[k] - mean; vs += d * d; }
#pragma unroll
  for (int off = 32; off > 0; off >>= 1) vs += __shfl_xor(vs, off, 64);
  const float rs = rsqrtf(vs * (1.f / 768.f) + 1e-5f);

#pragma unroll
  for (int c = 0; c < 3; ++c) {
    int idx = c * 256 + lane * 4;
    float4 gv = *reinterpret_cast<const float4*>(&g[idx]);
    float4 bv = *reinterpret_cast<const float4*>(&be[idx]);
    float r0 = (x[c*4+0] - mean) * rs * gv.x + bv.x;
    float r1 = (x[c*4+1] - mean) * rs * gv.y + bv.y;
    float r2 = (x[c*4+2] - mean) * rs * gv.z + bv.z;
    float r3 = (x[c*4+3] - mean) * rs * gv.w + bv.w;
    if (OUTBF) {
      short* op = (short*)outv + row * Ec + idx;
      s16x4 v = { f2bf(r0), f2bf(r1), f2bf(r2), f2bf(r3) };
      *reinterpret_cast<s16x4*>(op) = v;
    } else {
      float* op = (float*)outv + row * Ec + idx;
      *reinterpret_cast<float4*>(op) = make_float4(r0, r1, r2, r3);
    }
  }
}

// ---------------------------------------------------------------------------
extern "C" void kernel_launch(void* const* d_in, const int* in_sizes, int n_in,
                              void* d_out, int out_size, void* d_ws, size_t ws_size,
                              hipStream_t stream)
{
  const float* x       = (const float*)d_in[0];
  const float* sa_wqkv = (const float*)d_in[1];
  const float* sa_bqkv = (const float*)d_in[2];
  const float* sa_wo   = (const float*)d_in[3];
  const float* sa_bo   = (const float*)d_in[4];
  const float* sa_g    = (const float*)d_in[5];
  const float* sa_b    = (const float*)d_in[6];
  const float* ta_wqkv = (const float*)d_in[7];
  const float* ta_bqkv = (const float*)d_in[8];
  const float* ta_wo   = (const float*)d_in[9];
  const float* ta_bo   = (const float*)d_in[10];
  const float* ta_g    = (const float*)d_in[11];
  const float* ta_b    = (const float*)d_in[12];
  const float* f_w1    = (const float*)d_in[13];
  const float* f_b1    = (const float*)d_in[14];
  const float* f_w2    = (const float*)d_in[15];
  const float* f_b2    = (const float*)d_in[16];
  const float* f_g     = (const float*)d_in[17];
  const float* f_b     = (const float*)d_in[18];

  float* out = (float*)d_out;

  // ws layout (bytes): Xb bf16 2*ME | QKVH bf16 8*ME | U fp32 4*ME | Wt bf16
  constexpr size_t EE = (size_t)Ec * Ec;           // 589824
  constexpr size_t WTOT = 3*EE + EE + 3*EE + EE + 2*(size_t)Ec*FFc;  // 9,437,184
  const size_t need = 14 * ME + 2 * WTOT;
  if (ws_size < need) return;   // clean absmax failure signals ws shortage

  short* Xb  = (short*)d_ws;
  short* Qb  = Xb + ME;
  short* Kb  = Qb + ME;
  short* Vtb = Qb + 2 * ME;     // spatial: transposed-V; temporal: normal V
  short* Hb  = Qb;              // FFN hidden reuses [1ME,5ME)
  float* U   = (float*)(Xb + 5 * ME);
  short* Wtb = (short*)(U + ME);

  short* wt_sa_qkv = Wtb;
  short* wt_sa_wo  = wt_sa_qkv + 3 * EE;
  short* wt_ta_qkv = wt_sa_wo  + EE;
  short* wt_ta_wo  = wt_ta_qkv + 3 * EE;
  short* wt_f_w1   = wt_ta_wo  + EE;
  short* wt_f_w2   = wt_f_w1   + (size_t)Ec * FFc;

  // ---- weight prep + input convert ----
  wtrans_kernel<<<dim3(12, 12, 3), 256, 0, stream>>>(sa_wqkv, wt_sa_qkv, Ec, Ec);
  wtrans_kernel<<<dim3(12, 12, 1), 256, 0, stream>>>(sa_wo,   wt_sa_wo,  Ec, Ec);
  wtrans_kernel<<<dim3(12, 12, 3), 256, 0, stream>>>(ta_wqkv, wt_ta_qkv, Ec, Ec);
  wtrans_kernel<<<dim3(12, 12, 1), 256, 0, stream>>>(ta_wo,   wt_ta_wo,  Ec, Ec);
  wtrans_kernel<<<dim3(48, 12, 1), 256, 0, stream>>>(f_w1,    wt_f_w1,   Ec, FFc);
  wtrans_kernel<<<dim3(12, 48, 1), 256, 0, stream>>>(f_w2,    wt_f_w2,   FFc, Ec);
  f2bf_kernel<<<(int)(ME / 8 / 256), 256, 0, stream>>>(x, Xb, (int)(ME / 8));

  const int MT = Mrows / 256;                  // 64
  const dim3 gQKV(MT * (Ec / 256), 1, 3);      // 192 x 3
  const dim3 gSQ (MT * (Ec / 256), 1, 1);      // 192
  const dim3 gFF1(MT * (FFc / 256), 1, 1);     // 768

  // ---- Stage A: spatial attention ----
  gemm256_kernel<4><<<gQKV, 512, 0, stream>>>(Xb, wt_sa_qkv, sa_bqkv, nullptr, Qb, Vtb, Mrows, Ec, Ec);
  spatial_attn_kernel<<<dim3(Bc * Sc, Hc, 2), 256, 0, stream>>>(Qb, Kb, Vtb, Qb);
  gemm256_kernel<2><<<gSQ, 512, 0, stream>>>(Qb, wt_sa_wo, sa_bo, x, U, nullptr, Mrows, Ec, Ec);
  layernorm_kernel<true><<<Mrows / 4, 256, 0, stream>>>(U, sa_g, sa_b, Xb);

  // ---- Stage B: temporal attention ----
  gemm256_kernel<0><<<gQKV, 512, 0, stream>>>(Xb, wt_ta_qkv, ta_bqkv, nullptr, Qb, nullptr, Mrows, Ec, Ec);
  temporal_attn_kernel<<<Bc * Pc, 192, 0, stream>>>(Qb, Kb, Vtb, Qb);
  gemm256_kernel<3><<<gSQ, 512, 0, stream>>>(Qb, wt_ta_wo, ta_bo, Xb, U, nullptr, Mrows, Ec, Ec);
  layernorm_kernel<true><<<Mrows / 4, 256, 0, stream>>>(U, ta_g, ta_b, Xb);

  // ---- Stage C: FFN ----
  gemm256_kernel<1><<<gFF1, 512, 0, stream>>>(Xb, wt_f_w1, f_b1, nullptr, Hb, nullptr, Mrows, FFc, Ec);
  gemm256_kernel<3><<<gSQ, 512, 0, stream>>>(Hb, wt_f_w2, f_b2, Xb, U, nullptr, Mrows, Ec, FFc);
  layernorm_kernel<false><<<Mrows / 4, 256, 0, stream>>>(U, f_g, f_b, out);
}

// Round 7
// 613.507 us; speedup vs baseline: 3.3245x; 1.0484x over previous
//
#include <hip/hip_runtime.h>
#include <hip/hip_bf16.h>
#include <math.h>

// Problem constants
constexpr int Bc = 4, Sc = 16, Pc = 256, Ec = 768, Hc = 12, HDc = 64, FFc = 3072;
constexpr int Mrows = Bc * Sc * Pc;              // 16384 token rows
constexpr size_t ME = (size_t)Mrows * Ec;        // 12,582,912 elements

typedef __attribute__((ext_vector_type(4))) float f32x4;
typedef __attribute__((ext_vector_type(8))) short s16x8;
typedef __attribute__((ext_vector_type(4))) short s16x4;

__device__ __forceinline__ short f2bf(float f) {
  union { float f; unsigned u; } v; v.f = f;
  unsigned r = (v.u + 0x7FFFu + ((v.u >> 16) & 1u)) >> 16;  // RNE
  return (short)r;
}
__device__ __forceinline__ float bf2f(short s) {
  union { unsigned u; float f; } v; v.u = ((unsigned)(unsigned short)s) << 16;
  return v.f;
}

// async global->LDS, 16B per lane; lds dest must be wave-uniform base.
__device__ __forceinline__ void async16(const void* g, void* l) {
  __builtin_amdgcn_global_load_lds(
      (const __attribute__((address_space(1))) unsigned int*)g,
      (__attribute__((address_space(3))) unsigned int*)l, 16, 0, 0);
}

// ---------------------------------------------------------------------------
// fp32 -> bf16 convert (vectorized, 8 elems/thread)
// ---------------------------------------------------------------------------
__global__ __launch_bounds__(256)
void f2bf_kernel(const float* __restrict__ in, short* __restrict__ out, int n8)
{
  int i = blockIdx.x * 256 + threadIdx.x;
  if (i >= n8) return;
  const float4* p = reinterpret_cast<const float4*>(in + (size_t)i * 8);
  float4 a = p[0], b = p[1];
  s16x8 o = { f2bf(a.x), f2bf(a.y), f2bf(a.z), f2bf(a.w),
              f2bf(b.x), f2bf(b.y), f2bf(b.z), f2bf(b.w) };
  *reinterpret_cast<s16x8*>(out + (size_t)i * 8) = o;
}

// ---------------------------------------------------------------------------
// Weight transpose-convert: W fp32 [K][N] -> Wt bf16 [N][K].
// ---------------------------------------------------------------------------
__global__ __launch_bounds__(256)
void wtrans_kernel(const float* __restrict__ Wg, short* __restrict__ Wtg,
                   int K, int N)
{
  const int z = blockIdx.z;
  const float* W  = Wg  + (size_t)z * K * N;
  short*       Wt = Wtg + (size_t)z * N * K;
  const int n0 = blockIdx.x * 64, k0 = blockIdx.y * 64;
  const int t = threadIdx.x;
  const int n  = n0 + (t >> 2);
  const int kc = k0 + (t & 3) * 16;
  short buf[16];
#pragma unroll
  for (int i = 0; i < 16; ++i)
    buf[i] = f2bf(W[(size_t)(kc + i) * N + n]);
  *reinterpret_cast<s16x8*>(&Wt[(size_t)n * K + kc])     = *reinterpret_cast<s16x8*>(&buf[0]);
  *reinterpret_cast<s16x8*>(&Wt[(size_t)n * K + kc + 8]) = *reinterpret_cast<s16x8*>(&buf[8]);
}

// ---------------------------------------------------------------------------
// GEMM, 8-phase template (T1+T2+T3+T4+T5):
// C = A[M,K](bf16) * Wt[z][N,K](bf16)^T + bias[z]
// BMT=2: 256x256 tile, per-wave 128x64 (acc[8][4]), LDS 128KB.
// BMT=1: 128x256 tile, per-wave  64x64 (acc[4][4]), LDS  96KB.
// 512 threads = 8 waves (2M x 4N); BK=64; XOR-16B LDS swizzle both-sides;
// 8 phases per iter (2 K-tiles), counted vmcnt(4) at phases 4/8 only.
// OUT: 0 bf16 | 1 bf16+relu | 2 f32 + f32 residual | 3 f32 + bf16 residual
//      4 QKV-A mode: z<2 bf16 normal, z==2 writes transposed-V layout to vt
// ---------------------------------------------------------------------------
#define LDFRAG(base, row, kc) \
  (*reinterpret_cast<const s16x8*>((base) + (row) * 128 + ((((kc) ^ ((row) & 7)) << 4))))

#define PH_READS(Aslot, Bslot, q, LDB) \
  do { \
    if (LDB) { \
      _Pragma("unroll") \
      for (int nj = 0; nj < 4; ++nj) { \
        bfr[nj][0] = LDFRAG((Bslot), wc * 64 + nj * 16 + l16, g); \
        bfr[nj][1] = LDFRAG((Bslot), wc * 64 + nj * 16 + l16, 4 + g); \
      } \
    } \
    _Pragma("unroll") \
    for (int mi = 0; mi < BMT; ++mi) { \
      const int arow = wr * (BMT * 64) + ((q) * BMT + mi) * 16 + l16; \
      afr[mi][0] = LDFRAG((Aslot), arow, g); \
      afr[mi][1] = LDFRAG((Aslot), arow, 4 + g); \
    } \
  } while (0)

#define PH_SYNC_MMA(q) \
  do { \
    __builtin_amdgcn_sched_barrier(0); \
    __builtin_amdgcn_s_barrier(); \
    asm volatile("s_waitcnt lgkmcnt(0)" ::: "memory"); \
    __builtin_amdgcn_sched_barrier(0); \
    __builtin_amdgcn_s_setprio(1); \
    _Pragma("unroll") \
    for (int mi = 0; mi < BMT; ++mi) \
      _Pragma("unroll") \
      for (int nj = 0; nj < 4; ++nj) { \
        acc[(q) * BMT + mi][nj] = __builtin_amdgcn_mfma_f32_16x16x32_bf16( \
            afr[mi][0], bfr[nj][0], acc[(q) * BMT + mi][nj], 0, 0, 0); \
        acc[(q) * BMT + mi][nj] = __builtin_amdgcn_mfma_f32_16x16x32_bf16( \
            afr[mi][1], bfr[nj][1], acc[(q) * BMT + mi][nj], 0, 0, 0); \
      } \
    __builtin_amdgcn_s_setprio(0); \
  } while (0)

#define PH_END \
  do { __builtin_amdgcn_s_barrier(); __builtin_amdgcn_sched_barrier(0); } while (0)

#define PH_END_VM \
  do { \
    asm volatile("s_waitcnt vmcnt(4)" ::: "memory"); \
    __builtin_amdgcn_sched_barrier(0); \
    __builtin_amdgcn_s_barrier(); \
    __builtin_amdgcn_sched_barrier(0); \
  } while (0)

template<int OUT, int BMT>
__global__ __launch_bounds__(512, 2)
void gemm256_kernel(const short* __restrict__ A, const short* __restrict__ Wt,
                    const float* __restrict__ biasg, const void* __restrict__ resv,
                    void* __restrict__ Cg, short* __restrict__ vt,
                    int M, int N, int K)
{
  constexpr int ASZ = BMT * 16384;
  __shared__ char smem[2 * (ASZ + 32768)];
  const int z = blockIdx.z;
  const short* __restrict__ Wz = Wt + (size_t)z * (size_t)N * K;
  const float* __restrict__ bz = biasg + (size_t)z * N;

  // T1: bijective XCD swizzle (all grids are multiples of 8)
  const int nwg = gridDim.x;
  const int swz = ((int)blockIdx.x & 7) * (nwg >> 3) + ((int)blockIdx.x >> 3);
  const int NT = N >> 8;
  const int bm = (swz / NT) * (BMT * 128);
  const int bn = (swz % NT) << 8;

  const int tid  = threadIdx.x;
  const int lane = tid & 63;
  const int wid  = tid >> 6;
  const int wr   = wid >> 2;        // 0..1
  const int wc   = wid & 3;         // 0..3
  const int l16  = lane & 15;
  const int g    = lane >> 4;

  char* const As0 = smem;
  char* const Bs0 = smem + ASZ;
  char* const As1 = smem + ASZ + 32768;
  char* const Bs1 = smem + 2 * ASZ + 32768;

  // staging: lane covers (row = lane>>3, chunk = lane&7) of a 1KB wave region;
  // source chunk inverse-swizzled so LDS-linear + swizzled read match (#21).
  const int srow = lane >> 3;
  const int scol = ((lane & 7) ^ srow) * 8;
  const int ldso = wid * 1024;

  auto stageG = [&](const short* __restrict__ G, int grow0, int k0, char* ldsHalf) {
    const size_t r0 = (size_t)(grow0 + wid * 8 + srow);
    async16(G + r0 * K + (k0 + scol), ldsHalf + ldso);
    async16(G + (r0 + 64) * K + (k0 + scol), ldsHalf + 8192 + ldso);
  };

  f32x4 acc[BMT * 4][4];
  s16x8 bfr[4][2];
  s16x8 afr[BMT][2];
#pragma unroll
  for (int mi = 0; mi < BMT * 4; ++mi)
#pragma unroll
    for (int nj = 0; nj < 4; ++nj) acc[mi][nj] = f32x4{0.f, 0.f, 0.f, 0.f};

  const int ntile = K >> 6;
  const int nit   = ntile >> 1;

  // prologue: tile0 A+B -> slot0, tile1 B -> slot1
  stageG(A, bm, 0, As0);
  if (BMT == 2) stageG(A, bm + 128, 0, As0 + 16384);
  stageG(Wz, bn,       0,  Bs0);
  stageG(Wz, bn + 128, 0,  Bs0 + 16384);
  stageG(Wz, bn,       64, Bs1);
  stageG(Wz, bn + 128, 64, Bs1 + 16384);
  asm volatile("s_waitcnt vmcnt(4)" ::: "memory");
  __builtin_amdgcn_sched_barrier(0);
  __builtin_amdgcn_s_barrier();

  for (int j = 0; j < nit; ++j) {
    const int t1k = (2 * j + 1) << 6;
    const int t2k = (2 * j + 2) << 6;
    const int t3k = (2 * j + 3) << 6;
    const bool s2 = (2 * j + 2) < ntile;
    const bool s3 = (2 * j + 3) < ntile;

    // ---- K-tile 2j (slot0), phases 1-4 ----
    PH_READS(As0, Bs0, 0, true);
    stageG(A, bm, t1k, As1);                       // A(t1) h0 -> slot1
    PH_SYNC_MMA(0);
    PH_END;

    PH_READS(As0, Bs0, 1, false);
    if (BMT == 2) stageG(A, bm + 128, t1k, As1 + 16384);   // A(t1) h1
    PH_SYNC_MMA(1);
    PH_END;

    PH_READS(As0, Bs0, 2, false);
    if (s2) stageG(Wz, bn, t2k, Bs0);              // B(t2) h0 (Bs0 free since ph1)
    PH_SYNC_MMA(2);
    PH_END;

    PH_READS(As0, Bs0, 3, false);
    if (s2) stageG(Wz, bn + 128, t2k, Bs0 + 16384);// B(t2) h1
    PH_SYNC_MMA(3);
    PH_END_VM;                                     // forces A(t1), B(t1) landed

    // ---- K-tile 2j+1 (slot1), phases 5-8 ----
    PH_READS(As1, Bs1, 0, true);
    if (s2) stageG(A, bm, t2k, As0);               // A(t2) h0 (As0 free since ph4)
    PH_SYNC_MMA(0);
    PH_END;

    PH_READS(As1, Bs1, 1, false);
    if (BMT == 2) { if (s2) stageG(A, bm + 128, t2k, As0 + 16384); }
    PH_SYNC_MMA(1);
    PH_END;

    PH_READS(As1, Bs1, 2, false);
    if (s3) stageG(Wz, bn, t3k, Bs1);              // B(t3) h0 (Bs1 free since ph5)
    PH_SYNC_MMA(2);
    PH_END;

    PH_READS(As1, Bs1, 3, false);
    if (s3) stageG(Wz, bn + 128, t3k, Bs1 + 16384);// B(t3) h1
    PH_SYNC_MMA(3);
    PH_END_VM;                                     // forces B(t2), A(t2) landed
  }

  const float* resf = (const float*)resv;
  const short* resb = (const short*)resv;
  short* Cb = (short*)Cg + (size_t)z * (size_t)M * N;
  float* Cf = (float*)Cg + (size_t)z * (size_t)M * N;

#pragma unroll
  for (int mi = 0; mi < BMT * 4; ++mi) {
    const int row0 = bm + wr * (BMT * 64) + mi * 16 + g * 4;
#pragma unroll
    for (int nj = 0; nj < 4; ++nj) {
      const int col = bn + wc * 64 + nj * 16 + l16;
      if (OUT == 4 && z == 2) {
        // transposed-V: Vt[(bs*12+h)*64 + d][p], 4 consecutive p per lane
        const int bs2 = row0 >> 8, p0 = row0 & 255;
        const int h2 = col >> 6,  d2 = col & 63;
        const float bias = bz[col];
        s16x4 v = { f2bf(acc[mi][nj][0] + bias), f2bf(acc[mi][nj][1] + bias),
                    f2bf(acc[mi][nj][2] + bias), f2bf(acc[mi][nj][3] + bias) };
        *reinterpret_cast<s16x4*>(
            &vt[(((size_t)bs2 * 12 + h2) * 64 + d2) * 256 + p0]) = v;
      } else {
        const float bias = bz[col];
#pragma unroll
        for (int r = 0; r < 4; ++r) {
          float v = acc[mi][nj][r] + bias;
          size_t idx = (size_t)(row0 + r) * N + col;
          if (OUT == 2) v += resf[idx];
          if (OUT == 3) v += bf2f(resb[idx]);
          if (OUT == 1) v = fmaxf(v, 0.f);
          if (OUT == 2 || OUT == 3) Cf[idx] = v;
          else                      Cb[idx] = f2bf(v);
        }
      }
    }
  }
}

// ---------------------------------------------------------------------------
// Spatial attention, MFMA flash, barrier-free:
// block = (b*S+s, h, qhalf); 4 waves x 32 queries. K and V fragments read
// directly from global per lane (L1/L2-resident slabs); only P goes through
// per-wave LDS (4 KB, XOR-swizzled). No __syncthreads anywhere.
// ---------------------------------------------------------------------------
__global__ __launch_bounds__(256, 3)
void spatial_attn_kernel(const short* __restrict__ Qg, const short* __restrict__ Kg,
                         const short* __restrict__ Vt, short* __restrict__ Og)
{
  const int bs = blockIdx.x;   // 0..63
  const int h  = blockIdx.y;   // 0..11

  __shared__ short Pl[4 * 32 * 64];   // 16 KB total, per-wave 4 KB

  const int tid  = threadIdx.x;
  const int lane = tid & 63;
  const int wid  = tid >> 6;
  const int l16  = lane & 15;
  const int g    = lane >> 4;
  const int q0   = blockIdx.z * 128 + wid * 32;
  char* Pw = (char*)Pl + wid * 4096;

  const size_t rowbase = (size_t)(bs * 256) * 768 + h * 64;   // + row*768 + d
  const size_t vbase   = ((size_t)bs * 12 + h) * 64 * 256;    // Vt[d][key]

  // Q fragments (per-lane 16B global loads), held in registers
  s16x8 qa[2][2];
#pragma unroll
  for (int m = 0; m < 2; ++m)
#pragma unroll
    for (int ks = 0; ks < 2; ++ks)
      qa[m][ks] = *reinterpret_cast<const s16x8*>(
          &Qg[rowbase + (size_t)(q0 + m * 16 + l16) * 768 + ks * 32 + g * 8]);

  float mrun[2][4], lrun[2][4];
  f32x4 oac[2][4];
#pragma unroll
  for (int m = 0; m < 2; ++m)
#pragma unroll
    for (int r = 0; r < 4; ++r) { mrun[m][r] = -INFINITY; lrun[m][r] = 0.f; }
#pragma unroll
  for (int m = 0; m < 2; ++m)
#pragma unroll
    for (int n = 0; n < 4; ++n) oac[m][n] = f32x4{0.f, 0.f, 0.f, 0.f};

#pragma unroll
  for (int t = 0; t < 4; ++t) {
    const int key0 = t * 64;
    // S = Q K^T (32q x 64k per wave), K frags straight from global
    f32x4 sc[2][4];
#pragma unroll
    for (int m = 0; m < 2; ++m)
#pragma unroll
      for (int n = 0; n < 4; ++n) sc[m][n] = f32x4{0.f, 0.f, 0.f, 0.f};
#pragma unroll
    for (int ks = 0; ks < 2; ++ks) {
      s16x8 kf[4];
#pragma unroll
      for (int n = 0; n < 4; ++n) {
        const int key = key0 + n * 16 + l16;
        kf[n] = *reinterpret_cast<const s16x8*>(
            &Kg[rowbase + (size_t)key * 768 + ks * 32 + g * 8]);
      }
#pragma unroll
      for (int m = 0; m < 2; ++m)
#pragma unroll
        for (int n = 0; n < 4; ++n)
          sc[m][n] = __builtin_amdgcn_mfma_f32_16x16x32_bf16(qa[m][ks], kf[n], sc[m][n], 0, 0, 0);
    }
#pragma unroll
    for (int m = 0; m < 2; ++m)
#pragma unroll
      for (int n = 0; n < 4; ++n)
#pragma unroll
        for (int r = 0; r < 4; ++r) sc[m][n][r] *= 0.125f;

    // online softmax: q = m*16 + g*4 + r, keys across n-frags + l16 lanes
#pragma unroll
    for (int m = 0; m < 2; ++m) {
#pragma unroll
      for (int r = 0; r < 4; ++r) {
        float mx = fmaxf(fmaxf(sc[m][0][r], sc[m][1][r]), fmaxf(sc[m][2][r], sc[m][3][r]));
#pragma unroll
        for (int mk = 1; mk < 16; mk <<= 1) mx = fmaxf(mx, __shfl_xor(mx, mk, 64));
        const float mnew = fmaxf(mrun[m][r], mx);
        const float corr = __expf(mrun[m][r] - mnew);
        mrun[m][r] = mnew;
        float rs = 0.f;
#pragma unroll
        for (int n = 0; n < 4; ++n) {
          float p = __expf(sc[m][n][r] - mnew);
          sc[m][n][r] = p;
          rs += p;
        }
#pragma unroll
        for (int mk = 1; mk < 16; mk <<= 1) rs += __shfl_xor(rs, mk, 64);
        lrun[m][r] = lrun[m][r] * corr + rs;
#pragma unroll
        for (int nd = 0; nd < 4; ++nd) oac[m][nd][r] *= corr;
      }
    }
    // P -> per-wave LDS (bf16, XOR-swizzled rows of 128B)
#pragma unroll
    for (int m = 0; m < 2; ++m)
#pragma unroll
      for (int n = 0; n < 4; ++n)
#pragma unroll
        for (int r = 0; r < 4; ++r) {
          const int q = m * 16 + g * 4 + r;
          const int key = n * 16 + l16;
          const int byte = q * 128 + (((key >> 3) ^ (q & 7)) * 16) + (key & 7) * 2;
          *reinterpret_cast<short*>(Pw + byte) = f2bf(sc[m][n][r]);
        }
    // O += P V  (V frags straight from global Vt)
#pragma unroll
    for (int ks = 0; ks < 2; ++ks) {
      s16x8 pa[2], vf[4];
#pragma unroll
      for (int m = 0; m < 2; ++m) {
        const int q = m * 16 + l16;
        const int s = ks * 4 + g;
        pa[m] = *reinterpret_cast<const s16x8*>(Pw + q * 128 + ((s ^ (q & 7)) * 16));
      }
#pragma unroll
      for (int nd = 0; nd < 4; ++nd) {
        const int d = nd * 16 + l16;
        const int key = key0 + ks * 32 + g * 8;
        vf[nd] = *reinterpret_cast<const s16x8*>(&Vt[vbase + (size_t)d * 256 + key]);
      }
#pragma unroll
      for (int m = 0; m < 2; ++m)
#pragma unroll
        for (int nd = 0; nd < 4; ++nd)
          oac[m][nd] = __builtin_amdgcn_mfma_f32_16x16x32_bf16(pa[m], vf[nd], oac[m][nd], 0, 0, 0);
    }
  }

  // normalize, stage O through per-wave LDS, vectorized global write
#pragma unroll
  for (int m = 0; m < 2; ++m)
#pragma unroll
    for (int r = 0; r < 4; ++r) {
      const float inv = 1.f / lrun[m][r];
#pragma unroll
      for (int nd = 0; nd < 4; ++nd) oac[m][nd][r] *= inv;
    }
#pragma unroll
  for (int m = 0; m < 2; ++m)
#pragma unroll
    for (int nd = 0; nd < 4; ++nd)
#pragma unroll
      for (int r = 0; r < 4; ++r) {
        const int q = m * 16 + g * 4 + r;
        const int d = nd * 16 + l16;
        const int byte = q * 128 + (((d >> 3) ^ (q & 7)) * 16) + (d & 7) * 2;
        *reinterpret_cast<short*>(Pw + byte) = f2bf(oac[m][nd][r]);
      }
#pragma unroll
  for (int it = 0; it < 4; ++it) {
    const int slot = it * 64 + lane;          // 0..255 -> 32q x 4 slots
    const int q = slot >> 3, sl = slot & 7;
    const int d0 = (sl ^ (q & 7)) * 8;
    s16x8 v = *reinterpret_cast<const s16x8*>(Pw + slot * 16);
    *reinterpret_cast<s16x8*>(
        &Og[rowbase + (size_t)(q0 + q) * 768 + d0]) = v;
  }
}

// ---------------------------------------------------------------------------
// Temporal attention (causal over S=16): per (b,p) block, 192 threads.
// K,V staged in LDS (48 KB, coalesced 16B chunks, h-interleaved subtile
// layout -> conflict-free compute reads). thread = (i = tid/12, h = tid%12)
// so Q loads / O stores are h-contiguous. j-loop runs entirely from LDS.
// ---------------------------------------------------------------------------
__global__ __launch_bounds__(192)
void temporal_attn_kernel(const short* __restrict__ Qg, const short* __restrict__ Kg,
                          const short* __restrict__ Vg, short* __restrict__ Og)
{
  const int bp = blockIdx.x;
  const int b = bp >> 8, p = bp & 255;

  __shared__ short Ks[16 * 768];   // 24 KB
  __shared__ short Vs[16 * 768];   // 24 KB

  const int tid = threadIdx.x;
  const size_t gbase = ((size_t)(b * 16) * 256 + p) * 768;
  constexpr int SROW = 256 * 768;  // global row stride (s dimension)

  // stage K,V: 16 rows x 96 chunks of 16B each; LDS slot (c*12 + h)*8 shorts
  {
    const int half = tid / 96;           // 0..1
    const int cc   = tid - half * 96;    // 0..95
    const int c    = cc & 7, hs = cc >> 3;
    const int ldso = (c * 12 + hs) * 8;  // shorts within a row
#pragma unroll
    for (int it = 0; it < 8; ++it) {
      const int s = it * 2 + half;
      const size_t ga = gbase + (size_t)s * SROW + cc * 8;
      *reinterpret_cast<s16x8*>(&Ks[s * 768 + ldso]) =
          *reinterpret_cast<const s16x8*>(&Kg[ga]);
      *reinterpret_cast<s16x8*>(&Vs[s * 768 + ldso]) =
          *reinterpret_cast<const s16x8*>(&Vg[ga]);
    }
  }
  __syncthreads();

  const int h = tid % 12, i = tid / 12;
  const float scale = 0.125f;
  const size_t qoff = gbase + (size_t)i * SROW + h * 64;

  float q[HDc];
#pragma unroll
  for (int c = 0; c < 8; ++c) {
    s16x8 v = *reinterpret_cast<const s16x8*>(&Qg[qoff + c * 8]);
#pragma unroll
    for (int e = 0; e < 8; ++e) q[c * 8 + e] = bf2f(v[e]) * scale;
  }

  float m = -INFINITY, l = 0.f;
  float o[HDc];
#pragma unroll
  for (int d = 0; d < HDc; ++d) o[d] = 0.f;

  for (int j = 0; j <= i; ++j) {
    const short* kr = &Ks[j * 768];
    float s = 0.f;
#pragma unroll
    for (int c = 0; c < 8; ++c) {
      s16x8 kv = *reinterpret_cast<const s16x8*>(kr + (c * 12 + h) * 8);
#pragma unroll
      for (int e = 0; e < 8; ++e) s += q[c * 8 + e] * bf2f(kv[e]);
    }
    float mn   = fmaxf(m, s);
    float corr = __expf(m - mn);
    float pw   = __expf(s - mn);
    l = l * corr + pw;
    const short* vr = &Vs[j * 768];
#pragma unroll
    for (int c = 0; c < 8; ++c) {
      s16x8 vv = *reinterpret_cast<const s16x8*>(vr + (c * 12 + h) * 8);
#pragma unroll
      for (int e = 0; e < 8; ++e)
        o[c * 8 + e] = fmaf(pw, bf2f(vv[e]), o[c * 8 + e] * corr);
    }
    m = mn;
  }
  const float inv = 1.f / l;
  short* op = &Og[qoff];
#pragma unroll
  for (int c = 0; c < 8; ++c) {
    s16x8 v;
#pragma unroll
    for (int e = 0; e < 8; ++e) v[e] = f2bf(o[c * 8 + e] * inv);
    *reinterpret_cast<s16x8*>(op + c * 8) = v;
  }
}

// ---------------------------------------------------------------------------
// LayerNorm over E=768: one wave per row, 4 rows per block.
// ---------------------------------------------------------------------------
template<bool OUTBF>
__global__ __launch_bounds__(256)
void layernorm_kernel(const float* __restrict__ U, const float* __restrict__ g,
                      const float* __restrict__ be, void* __restrict__ outv)
{
  const int tid  = threadIdx.x;
  const int lane = tid & 63, w = tid >> 6;
  const size_t row = (size_t)blockIdx.x * 4 + w;
  const float* u = U + row * Ec;

  float x[12];
#pragma unroll
  for (int c = 0; c < 3; ++c) {
    float4 v = *reinterpret_cast<const float4*>(&u[c * 256 + lane * 4]);
    x[c*4+0] = v.x; x[c*4+1] = v.y; x[c*4+2] = v.z; x[c*4+3] = v.w;
  }
  float s = 0.f;
#pragma unroll
  for (int k = 0; k < 12; ++k) s += x[k];
#pragma unroll
  for (int off = 32; off > 0; off >>= 1) s += __shfl_xor(s, off, 64);
  const float mean = s * (1.f / 768.f);

  float vs = 0.f;
#pragma unroll
  for (int k = 0; k < 12; ++k) { float d = x[k] - mean; vs += d * d; }
#pragma unroll
  for (int off = 32; off > 0; off >>= 1) vs += __shfl_xor(vs, off, 64);
  const float rs = rsqrtf(vs * (1.f / 768.f) + 1e-5f);

#pragma unroll
  for (int c = 0; c < 3; ++c) {
    int idx = c * 256 + lane * 4;
    float4 gv = *reinterpret_cast<const float4*>(&g[idx]);
    float4 bv = *reinterpret_cast<const float4*>(&be[idx]);
    float r0 = (x[c*4+0] - mean) * rs * gv.x + bv.x;
    float r1 = (x[c*4+1] - mean) * rs * gv.y + bv.y;
    float r2 = (x[c*4+2] - mean) * rs * gv.z + bv.z;
    float r3 = (x[c*4+3] - mean) * rs * gv.w + bv.w;
    if (OUTBF) {
      short* op = (short*)outv + row * Ec + idx;
      s16x4 v = { f2bf(r0), f2bf(r1), f2bf(r2), f2bf(r3) };
      *reinterpret_cast<s16x4*>(op) = v;
    } else {
      float* op = (float*)outv + row * Ec + idx;
      *reinterpret_cast<float4*>(op) = make_float4(r0, r1, r2, r3);
    }
  }
}

// ---------------------------------------------------------------------------
extern "C" void kernel_launch(void* const* d_in, const int* in_sizes, int n_in,
                              void* d_out, int out_size, void* d_ws, size_t ws_size,
                              hipStream_t stream)
{
  const float* x       = (const float*)d_in[0];
  const float* sa_wqkv = (const float*)d_in[1];
  const float* sa_bqkv = (const float*)d_in[2];
  const float* sa_wo   = (const float*)d_in[3];
  const float* sa_bo   = (const float*)d_in[4];
  const float* sa_g    = (const float*)d_in[5];
  const float* sa_b    = (const float*)d_in[6];
  const float* ta_wqkv = (const float*)d_in[7];
  const float* ta_bqkv = (const float*)d_in[8];
  const float* ta_wo   = (const float*)d_in[9];
  const float* ta_bo   = (const float*)d_in[10];
  const float* ta_g    = (const float*)d_in[11];
  const float* ta_b    = (const float*)d_in[12];
  const float* f_w1    = (const float*)d_in[13];
  const float* f_b1    = (const float*)d_in[14];
  const float* f_w2    = (const float*)d_in[15];
  const float* f_b2    = (const float*)d_in[16];
  const float* f_g     = (const float*)d_in[17];
  const float* f_b     = (const float*)d_in[18];

  float* out = (float*)d_out;

  // ws layout (bytes): Xb bf16 2*ME | QKVH bf16 8*ME | U fp32 4*ME | Wt bf16
  constexpr size_t EE = (size_t)Ec * Ec;           // 589824
  constexpr size_t WTOT = 3*EE + EE + 3*EE + EE + 2*(size_t)Ec*FFc;  // 9,437,184
  const size_t need = 14 * ME + 2 * WTOT;
  if (ws_size < need) return;   // clean absmax failure signals ws shortage

  short* Xb  = (short*)d_ws;
  short* Qb  = Xb + ME;
  short* Kb  = Qb + ME;
  short* Vtb = Qb + 2 * ME;     // spatial: transposed-V; temporal: normal V
  short* Hb  = Qb;              // FFN hidden reuses [1ME,5ME)
  float* U   = (float*)(Xb + 5 * ME);
  short* Wtb = (short*)(U + ME);

  short* wt_sa_qkv = Wtb;
  short* wt_sa_wo  = wt_sa_qkv + 3 * EE;
  short* wt_ta_qkv = wt_sa_wo  + EE;
  short* wt_ta_wo  = wt_ta_qkv + 3 * EE;
  short* wt_f_w1   = wt_ta_wo  + EE;
  short* wt_f_w2   = wt_f_w1   + (size_t)Ec * FFc;

  // ---- weight prep + input convert ----
  wtrans_kernel<<<dim3(12, 12, 3), 256, 0, stream>>>(sa_wqkv, wt_sa_qkv, Ec, Ec);
  wtrans_kernel<<<dim3(12, 12, 1), 256, 0, stream>>>(sa_wo,   wt_sa_wo,  Ec, Ec);
  wtrans_kernel<<<dim3(12, 12, 3), 256, 0, stream>>>(ta_wqkv, wt_ta_qkv, Ec, Ec);
  wtrans_kernel<<<dim3(12, 12, 1), 256, 0, stream>>>(ta_wo,   wt_ta_wo,  Ec, Ec);
  wtrans_kernel<<<dim3(48, 12, 1), 256, 0, stream>>>(f_w1,    wt_f_w1,   Ec, FFc);
  wtrans_kernel<<<dim3(12, 48, 1), 256, 0, stream>>>(f_w2,    wt_f_w2,   FFc, Ec);
  f2bf_kernel<<<(int)(ME / 8 / 256), 256, 0, stream>>>(x, Xb, (int)(ME / 8));

  // grids: BMT=2 -> (M/256)*(N/256); BMT=1 -> (M/128)*(N/256)
  const dim3 gQKV((Mrows / 256) * (Ec / 256), 1, 3);      // 192 x3
  const dim3 gSQ ((Mrows / 128) * (Ec / 256), 1, 1);      // 384 (BMT=1)
  const dim3 gFF1((Mrows / 256) * (FFc / 256), 1, 1);     // 768

  // ---- Stage A: spatial attention ----
  gemm256_kernel<4, 2><<<gQKV, 512, 0, stream>>>(Xb, wt_sa_qkv, sa_bqkv, nullptr, Qb, Vtb, Mrows, Ec, Ec);
  spatial_attn_kernel<<<dim3(Bc * Sc, Hc, 2), 256, 0, stream>>>(Qb, Kb, Vtb, Qb);
  gemm256_kernel<2, 1><<<gSQ, 512, 0, stream>>>(Qb, wt_sa_wo, sa_bo, x, U, nullptr, Mrows, Ec, Ec);
  layernorm_kernel<true><<<Mrows / 4, 256, 0, stream>>>(U, sa_g, sa_b, Xb);

  // ---- Stage B: temporal attention ----
  gemm256_kernel<0, 2><<<gQKV, 512, 0, stream>>>(Xb, wt_ta_qkv, ta_bqkv, nullptr, Qb, nullptr, Mrows, Ec, Ec);
  temporal_attn_kernel<<<Bc * Pc, 192, 0, stream>>>(Qb, Kb, Vtb, Qb);
  gemm256_kernel<3, 1><<<gSQ, 512, 0, stream>>>(Qb, wt_ta_wo, ta_bo, Xb, U, nullptr, Mrows, Ec, Ec);
  layernorm_kernel<true><<<Mrows / 4, 256, 0, stream>>>(U, ta_g, ta_b, Xb);

  // ---- Stage C: FFN ----
  gemm256_kernel<1, 2><<<gFF1, 512, 0, stream>>>(Xb, wt_f_w1, f_b1, nullptr, Hb, nullptr, Mrows, FFc, Ec);
  gemm256_kernel<3, 1><<<gSQ, 512, 0, stream>>>(Hb, wt_f_w2, f_b2, Xb, U, nullptr, Mrows, Ec, FFc);
  layernorm_kernel<false><<<Mrows / 4, 256, 0, stream>>>(U, f_g, f_b, out);
}

// Round 8
// 578.078 us; speedup vs baseline: 3.5282x; 1.0613x over previous
//
#include <hip/hip_runtime.h>
#include <hip/hip_bf16.h>
#include <math.h>

// Problem constants
constexpr int Bc = 4, Sc = 16, Pc = 256, Ec = 768, Hc = 12, HDc = 64, FFc = 3072;
constexpr int Mrows = Bc * Sc * Pc;              // 16384 token rows
constexpr size_t ME = (size_t)Mrows * Ec;        // 12,582,912 elements

typedef __attribute__((ext_vector_type(4))) float f32x4;
typedef __attribute__((ext_vector_type(8))) short s16x8;
typedef __attribute__((ext_vector_type(4))) short s16x4;

__device__ __forceinline__ short f2bf(float f) {
  union { float f; unsigned u; } v; v.f = f;
  unsigned r = (v.u + 0x7FFFu + ((v.u >> 16) & 1u)) >> 16;  // RNE
  return (short)r;
}
__device__ __forceinline__ float bf2f(short s) {
  union { unsigned u; float f; } v; v.u = ((unsigned)(unsigned short)s) << 16;
  return v.f;
}

// async global->LDS, 16B per lane; lds dest must be wave-uniform base.
__device__ __forceinline__ void async16(const void* g, void* l) {
  __builtin_amdgcn_global_load_lds(
      (const __attribute__((address_space(1))) unsigned int*)g,
      (__attribute__((address_space(3))) unsigned int*)l, 16, 0, 0);
}

// ---------------------------------------------------------------------------
// Unified prep kernel: 6 weight transpose-converts + x->bf16, one dispatch.
// Transpose unit: 64x64 tile, 256 threads (4 lanes/row of 16 k-elems).
// Block ranges:
//   [0,432)    sa_qkv  3x(12x12)      [432,576)   sa_wo  12x12
//   [576,1008) ta_qkv                 [1008,1152) ta_wo
//   [1152,1728) f_w1 (K=768,N=3072) 12x48 tiles
//   [1728,2304) f_w2 (K=3072,N=768) 48x12 tiles
//   [2304,8448) f2bf of x (6144 blocks x 2048 elems)
// ---------------------------------------------------------------------------
__device__ __forceinline__ void wtrans_tile(const float* __restrict__ W,
                                            short* __restrict__ Wt,
                                            int K, int N, int n0, int k0, int t)
{
  const int n  = n0 + (t >> 2);
  const int kc = k0 + (t & 3) * 16;
  short buf[16];
#pragma unroll
  for (int i = 0; i < 16; ++i)
    buf[i] = f2bf(W[(size_t)(kc + i) * N + n]);
  *reinterpret_cast<s16x8*>(&Wt[(size_t)n * K + kc])     = *reinterpret_cast<s16x8*>(&buf[0]);
  *reinterpret_cast<s16x8*>(&Wt[(size_t)n * K + kc + 8]) = *reinterpret_cast<s16x8*>(&buf[8]);
}

__global__ __launch_bounds__(256)
void prep_kernel(const float* __restrict__ x, short* __restrict__ Xb,
                 const float* __restrict__ saqkv, short* __restrict__ wt_saqkv,
                 const float* __restrict__ sawo,  short* __restrict__ wt_sawo,
                 const float* __restrict__ taqkv, short* __restrict__ wt_taqkv,
                 const float* __restrict__ tawo,  short* __restrict__ wt_tawo,
                 const float* __restrict__ fw1,   short* __restrict__ wt_fw1,
                 const float* __restrict__ fw2,   short* __restrict__ wt_fw2)
{
  const int b = blockIdx.x;
  const int t = threadIdx.x;
  constexpr size_t EE = (size_t)Ec * Ec;

  if (b < 432) {
    const int z = b / 144, tl = b % 144;
    wtrans_tile(saqkv + (size_t)z * EE, wt_saqkv + (size_t)z * EE,
                Ec, Ec, (tl % 12) * 64, (tl / 12) * 64, t);
  } else if (b < 576) {
    const int tl = b - 432;
    wtrans_tile(sawo, wt_sawo, Ec, Ec, (tl % 12) * 64, (tl / 12) * 64, t);
  } else if (b < 1008) {
    const int z = (b - 576) / 144, tl = (b - 576) % 144;
    wtrans_tile(taqkv + (size_t)z * EE, wt_taqkv + (size_t)z * EE,
                Ec, Ec, (tl % 12) * 64, (tl / 12) * 64, t);
  } else if (b < 1152) {
    const int tl = b - 1008;
    wtrans_tile(tawo, wt_tawo, Ec, Ec, (tl % 12) * 64, (tl / 12) * 64, t);
  } else if (b < 1728) {
    const int tl = b - 1152;
    wtrans_tile(fw1, wt_fw1, Ec, FFc, (tl % 48) * 64, (tl / 48) * 64, t);
  } else if (b < 2304) {
    const int tl = b - 1728;
    wtrans_tile(fw2, wt_fw2, FFc, Ec, (tl % 12) * 64, (tl / 12) * 64, t);
  } else {
    const size_t i = (size_t)(b - 2304) * 256 + t;   // 8 elems each
    const float4* p = reinterpret_cast<const float4*>(x + i * 8);
    float4 a = p[0], bb = p[1];
    s16x8 o = { f2bf(a.x), f2bf(a.y), f2bf(a.z), f2bf(a.w),
                f2bf(bb.x), f2bf(bb.y), f2bf(bb.z), f2bf(bb.w) };
    *reinterpret_cast<s16x8*>(Xb + i * 8) = o;
  }
}

// ---------------------------------------------------------------------------
// GEMM, 8-phase template (T1+T2+T3+T4+T5):
// C = A[M,K](bf16) * Wt[z][N,K](bf16)^T + bias[z]
// BMT=2: 256x256 tile, per-wave 128x64 (acc[8][4]), LDS 128KB.
// BMT=1: 128x256 tile, per-wave  64x64 (acc[4][4]), LDS  96KB.
// 512 threads = 8 waves (2M x 4N); BK=64; XOR-16B LDS swizzle both-sides;
// 8 phases per iter (2 K-tiles), counted vmcnt(4) at phases 4/8 only.
// OUT: 0 bf16 | 1 bf16+relu | 3 bf16 store + bf16 residual
//      4 QKV-A mode: z<2 bf16 normal, z==2 writes transposed-V layout to vt
// ---------------------------------------------------------------------------
#define LDFRAG(base, row, kc) \
  (*reinterpret_cast<const s16x8*>((base) + (row) * 128 + ((((kc) ^ ((row) & 7)) << 4))))

#define PH_READS(Aslot, Bslot, q, LDB) \
  do { \
    if (LDB) { \
      _Pragma("unroll") \
      for (int nj = 0; nj < 4; ++nj) { \
        bfr[nj][0] = LDFRAG((Bslot), wc * 64 + nj * 16 + l16, g); \
        bfr[nj][1] = LDFRAG((Bslot), wc * 64 + nj * 16 + l16, 4 + g); \
      } \
    } \
    _Pragma("unroll") \
    for (int mi = 0; mi < BMT; ++mi) { \
      const int arow = wr * (BMT * 64) + ((q) * BMT + mi) * 16 + l16; \
      afr[mi][0] = LDFRAG((Aslot), arow, g); \
      afr[mi][1] = LDFRAG((Aslot), arow, 4 + g); \
    } \
  } while (0)

#define PH_SYNC_MMA(q) \
  do { \
    __builtin_amdgcn_sched_barrier(0); \
    __builtin_amdgcn_s_barrier(); \
    asm volatile("s_waitcnt lgkmcnt(0)" ::: "memory"); \
    __builtin_amdgcn_sched_barrier(0); \
    __builtin_amdgcn_s_setprio(1); \
    _Pragma("unroll") \
    for (int mi = 0; mi < BMT; ++mi) \
      _Pragma("unroll") \
      for (int nj = 0; nj < 4; ++nj) { \
        acc[(q) * BMT + mi][nj] = __builtin_amdgcn_mfma_f32_16x16x32_bf16( \
            afr[mi][0], bfr[nj][0], acc[(q) * BMT + mi][nj], 0, 0, 0); \
        acc[(q) * BMT + mi][nj] = __builtin_amdgcn_mfma_f32_16x16x32_bf16( \
            afr[mi][1], bfr[nj][1], acc[(q) * BMT + mi][nj], 0, 0, 0); \
      } \
    __builtin_amdgcn_s_setprio(0); \
  } while (0)

#define PH_END \
  do { __builtin_amdgcn_s_barrier(); __builtin_amdgcn_sched_barrier(0); } while (0)

#define PH_END_VM \
  do { \
    asm volatile("s_waitcnt vmcnt(4)" ::: "memory"); \
    __builtin_amdgcn_sched_barrier(0); \
    __builtin_amdgcn_s_barrier(); \
    __builtin_amdgcn_sched_barrier(0); \
  } while (0)

template<int OUT, int BMT>
__global__ __launch_bounds__(512, 2)
void gemm256_kernel(const short* __restrict__ A, const short* __restrict__ Wt,
                    const float* __restrict__ biasg, const void* __restrict__ resv,
                    void* __restrict__ Cg, short* __restrict__ vt,
                    int M, int N, int K)
{
  constexpr int ASZ = BMT * 16384;
  __shared__ char smem[2 * (ASZ + 32768)];
  const int z = blockIdx.z;
  const short* __restrict__ Wz = Wt + (size_t)z * (size_t)N * K;
  const float* __restrict__ bz = biasg + (size_t)z * N;

  // T1: bijective XCD swizzle (all grids are multiples of 8)
  const int nwg = gridDim.x;
  const int swz = ((int)blockIdx.x & 7) * (nwg >> 3) + ((int)blockIdx.x >> 3);
  const int NT = N >> 8;
  const int bm = (swz / NT) * (BMT * 128);
  const int bn = (swz % NT) << 8;

  const int tid  = threadIdx.x;
  const int lane = tid & 63;
  const int wid  = tid >> 6;
  const int wr   = wid >> 2;        // 0..1
  const int wc   = wid & 3;         // 0..3
  const int l16  = lane & 15;
  const int g    = lane >> 4;

  char* const As0 = smem;
  char* const Bs0 = smem + ASZ;
  char* const As1 = smem + ASZ + 32768;
  char* const Bs1 = smem + 2 * ASZ + 32768;

  // staging: lane covers (row = lane>>3, chunk = lane&7) of a 1KB wave region;
  // source chunk inverse-swizzled so LDS-linear + swizzled read match (#21).
  const int srow = lane >> 3;
  const int scol = ((lane & 7) ^ srow) * 8;
  const int ldso = wid * 1024;

  auto stageG = [&](const short* __restrict__ G, int grow0, int k0, char* ldsHalf) {
    const size_t r0 = (size_t)(grow0 + wid * 8 + srow);
    async16(G + r0 * K + (k0 + scol), ldsHalf + ldso);
    async16(G + (r0 + 64) * K + (k0 + scol), ldsHalf + 8192 + ldso);
  };

  f32x4 acc[BMT * 4][4];
  s16x8 bfr[4][2];
  s16x8 afr[BMT][2];
#pragma unroll
  for (int mi = 0; mi < BMT * 4; ++mi)
#pragma unroll
    for (int nj = 0; nj < 4; ++nj) acc[mi][nj] = f32x4{0.f, 0.f, 0.f, 0.f};

  const int ntile = K >> 6;
  const int nit   = ntile >> 1;

  // prologue: tile0 A+B -> slot0, tile1 B -> slot1
  stageG(A, bm, 0, As0);
  if (BMT == 2) stageG(A, bm + 128, 0, As0 + 16384);
  stageG(Wz, bn,       0,  Bs0);
  stageG(Wz, bn + 128, 0,  Bs0 + 16384);
  stageG(Wz, bn,       64, Bs1);
  stageG(Wz, bn + 128, 64, Bs1 + 16384);
  asm volatile("s_waitcnt vmcnt(4)" ::: "memory");
  __builtin_amdgcn_sched_barrier(0);
  __builtin_amdgcn_s_barrier();

  for (int j = 0; j < nit; ++j) {
    const int t1k = (2 * j + 1) << 6;
    const int t2k = (2 * j + 2) << 6;
    const int t3k = (2 * j + 3) << 6;
    const bool s2 = (2 * j + 2) < ntile;
    const bool s3 = (2 * j + 3) < ntile;

    // ---- K-tile 2j (slot0), phases 1-4 ----
    PH_READS(As0, Bs0, 0, true);
    stageG(A, bm, t1k, As1);                       // A(t1) h0 -> slot1
    PH_SYNC_MMA(0);
    PH_END;

    PH_READS(As0, Bs0, 1, false);
    if (BMT == 2) stageG(A, bm + 128, t1k, As1 + 16384);   // A(t1) h1
    PH_SYNC_MMA(1);
    PH_END;

    PH_READS(As0, Bs0, 2, false);
    if (s2) stageG(Wz, bn, t2k, Bs0);              // B(t2) h0 (Bs0 free since ph1)
    PH_SYNC_MMA(2);
    PH_END;

    PH_READS(As0, Bs0, 3, false);
    if (s2) stageG(Wz, bn + 128, t2k, Bs0 + 16384);// B(t2) h1
    PH_SYNC_MMA(3);
    PH_END_VM;                                     // forces A(t1), B(t1) landed

    // ---- K-tile 2j+1 (slot1), phases 5-8 ----
    PH_READS(As1, Bs1, 0, true);
    if (s2) stageG(A, bm, t2k, As0);               // A(t2) h0 (As0 free since ph4)
    PH_SYNC_MMA(0);
    PH_END;

    PH_READS(As1, Bs1, 1, false);
    if (BMT == 2) { if (s2) stageG(A, bm + 128, t2k, As0 + 16384); }
    PH_SYNC_MMA(1);
    PH_END;

    PH_READS(As1, Bs1, 2, false);
    if (s3) stageG(Wz, bn, t3k, Bs1);              // B(t3) h0 (Bs1 free since ph5)
    PH_SYNC_MMA(2);
    PH_END;

    PH_READS(As1, Bs1, 3, false);
    if (s3) stageG(Wz, bn + 128, t3k, Bs1 + 16384);// B(t3) h1
    PH_SYNC_MMA(3);
    PH_END_VM;                                     // forces B(t2), A(t2) landed
  }

  const short* resb = (const short*)resv;
  short* Cb = (short*)Cg + (size_t)z * (size_t)M * N;

#pragma unroll
  for (int mi = 0; mi < BMT * 4; ++mi) {
    const int row0 = bm + wr * (BMT * 64) + mi * 16 + g * 4;
#pragma unroll
    for (int nj = 0; nj < 4; ++nj) {
      const int col = bn + wc * 64 + nj * 16 + l16;
      if (OUT == 4 && z == 2) {
        // transposed-V: Vt[(bs*12+h)*64 + d][p], 4 consecutive p per lane
        const int bs2 = row0 >> 8, p0 = row0 & 255;
        const int h2 = col >> 6,  d2 = col & 63;
        const float bias = bz[col];
        s16x4 v = { f2bf(acc[mi][nj][0] + bias), f2bf(acc[mi][nj][1] + bias),
                    f2bf(acc[mi][nj][2] + bias), f2bf(acc[mi][nj][3] + bias) };
        *reinterpret_cast<s16x4*>(
            &vt[(((size_t)bs2 * 12 + h2) * 64 + d2) * 256 + p0]) = v;
      } else {
        const float bias = bz[col];
#pragma unroll
        for (int r = 0; r < 4; ++r) {
          float v = acc[mi][nj][r] + bias;
          size_t idx = (size_t)(row0 + r) * N + col;
          if (OUT == 3) v += bf2f(resb[idx]);
          if (OUT == 1) v = fmaxf(v, 0.f);
          Cb[idx] = f2bf(v);
        }
      }
    }
  }
}

// ---------------------------------------------------------------------------
// Spatial attention, MFMA flash, barrier-free:
// block = (b*S+s, h, qhalf); 4 waves x 32 queries. K and V fragments read
// directly from global per lane (L1/L2-resident slabs); only P goes through
// per-wave LDS (4 KB, XOR-swizzled). No __syncthreads anywhere.
// ---------------------------------------------------------------------------
__global__ __launch_bounds__(256, 3)
void spatial_attn_kernel(const short* __restrict__ Qg, const short* __restrict__ Kg,
                         const short* __restrict__ Vt, short* __restrict__ Og)
{
  const int bs = blockIdx.x;   // 0..63
  const int h  = blockIdx.y;   // 0..11

  __shared__ short Pl[4 * 32 * 64];   // 16 KB total, per-wave 4 KB

  const int tid  = threadIdx.x;
  const int lane = tid & 63;
  const int wid  = tid >> 6;
  const int l16  = lane & 15;
  const int g    = lane >> 4;
  const int q0   = blockIdx.z * 128 + wid * 32;
  char* Pw = (char*)Pl + wid * 4096;

  const size_t rowbase = (size_t)(bs * 256) * 768 + h * 64;   // + row*768 + d
  const size_t vbase   = ((size_t)bs * 12 + h) * 64 * 256;    // Vt[d][key]

  // Q fragments (per-lane 16B global loads), held in registers
  s16x8 qa[2][2];
#pragma unroll
  for (int m = 0; m < 2; ++m)
#pragma unroll
    for (int ks = 0; ks < 2; ++ks)
      qa[m][ks] = *reinterpret_cast<const s16x8*>(
          &Qg[rowbase + (size_t)(q0 + m * 16 + l16) * 768 + ks * 32 + g * 8]);

  float mrun[2][4], lrun[2][4];
  f32x4 oac[2][4];
#pragma unroll
  for (int m = 0; m < 2; ++m)
#pragma unroll
    for (int r = 0; r < 4; ++r) { mrun[m][r] = -INFINITY; lrun[m][r] = 0.f; }
#pragma unroll
  for (int m = 0; m < 2; ++m)
#pragma unroll
    for (int n = 0; n < 4; ++n) oac[m][n] = f32x4{0.f, 0.f, 0.f, 0.f};

#pragma unroll
  for (int t = 0; t < 4; ++t) {
    const int key0 = t * 64;
    // S = Q K^T (32q x 64k per wave), K frags straight from global
    f32x4 sc[2][4];
#pragma unroll
    for (int m = 0; m < 2; ++m)
#pragma unroll
      for (int n = 0; n < 4; ++n) sc[m][n] = f32x4{0.f, 0.f, 0.f, 0.f};
#pragma unroll
    for (int ks = 0; ks < 2; ++ks) {
      s16x8 kf[4];
#pragma unroll
      for (int n = 0; n < 4; ++n) {
        const int key = key0 + n * 16 + l16;
        kf[n] = *reinterpret_cast<const s16x8*>(
            &Kg[rowbase + (size_t)key * 768 + ks * 32 + g * 8]);
      }
#pragma unroll
      for (int m = 0; m < 2; ++m)
#pragma unroll
        for (int n = 0; n < 4; ++n)
          sc[m][n] = __builtin_amdgcn_mfma_f32_16x16x32_bf16(qa[m][ks], kf[n], sc[m][n], 0, 0, 0);
    }
#pragma unroll
    for (int m = 0; m < 2; ++m)
#pragma unroll
      for (int n = 0; n < 4; ++n)
#pragma unroll
        for (int r = 0; r < 4; ++r) sc[m][n][r] *= 0.125f;

    // online softmax: q = m*16 + g*4 + r, keys across n-frags + l16 lanes
#pragma unroll
    for (int m = 0; m < 2; ++m) {
#pragma unroll
      for (int r = 0; r < 4; ++r) {
        float mx = fmaxf(fmaxf(sc[m][0][r], sc[m][1][r]), fmaxf(sc[m][2][r], sc[m][3][r]));
#pragma unroll
        for (int mk = 1; mk < 16; mk <<= 1) mx = fmaxf(mx, __shfl_xor(mx, mk, 64));
        const float mnew = fmaxf(mrun[m][r], mx);
        const float corr = __expf(mrun[m][r] - mnew);
        mrun[m][r] = mnew;
        float rs = 0.f;
#pragma unroll
        for (int n = 0; n < 4; ++n) {
          float p = __expf(sc[m][n][r] - mnew);
          sc[m][n][r] = p;
          rs += p;
        }
#pragma unroll
        for (int mk = 1; mk < 16; mk <<= 1) rs += __shfl_xor(rs, mk, 64);
        lrun[m][r] = lrun[m][r] * corr + rs;
#pragma unroll
        for (int nd = 0; nd < 4; ++nd) oac[m][nd][r] *= corr;
      }
    }
    // P -> per-wave LDS (bf16, XOR-swizzled rows of 128B)
#pragma unroll
    for (int m = 0; m < 2; ++m)
#pragma unroll
      for (int n = 0; n < 4; ++n)
#pragma unroll
        for (int r = 0; r < 4; ++r) {
          const int q = m * 16 + g * 4 + r;
          const int key = n * 16 + l16;
          const int byte = q * 128 + (((key >> 3) ^ (q & 7)) * 16) + (key & 7) * 2;
          *reinterpret_cast<short*>(Pw + byte) = f2bf(sc[m][n][r]);
        }
    // O += P V  (V frags straight from global Vt)
#pragma unroll
    for (int ks = 0; ks < 2; ++ks) {
      s16x8 pa[2], vf[4];
#pragma unroll
      for (int m = 0; m < 2; ++m) {
        const int q = m * 16 + l16;
        const int s = ks * 4 + g;
        pa[m] = *reinterpret_cast<const s16x8*>(Pw + q * 128 + ((s ^ (q & 7)) * 16));
      }
#pragma unroll
      for (int nd = 0; nd < 4; ++nd) {
        const int d = nd * 16 + l16;
        const int key = key0 + ks * 32 + g * 8;
        vf[nd] = *reinterpret_cast<const s16x8*>(&Vt[vbase + (size_t)d * 256 + key]);
      }
#pragma unroll
      for (int m = 0; m < 2; ++m)
#pragma unroll
        for (int nd = 0; nd < 4; ++nd)
          oac[m][nd] = __builtin_amdgcn_mfma_f32_16x16x32_bf16(pa[m], vf[nd], oac[m][nd], 0, 0, 0);
    }
  }

  // normalize, stage O through per-wave LDS, vectorized global write
#pragma unroll
  for (int m = 0; m < 2; ++m)
#pragma unroll
    for (int r = 0; r < 4; ++r) {
      const float inv = 1.f / lrun[m][r];
#pragma unroll
      for (int nd = 0; nd < 4; ++nd) oac[m][nd][r] *= inv;
    }
#pragma unroll
  for (int m = 0; m < 2; ++m)
#pragma unroll
    for (int nd = 0; nd < 4; ++nd)
#pragma unroll
      for (int r = 0; r < 4; ++r) {
        const int q = m * 16 + g * 4 + r;
        const int d = nd * 16 + l16;
        const int byte = q * 128 + (((d >> 3) ^ (q & 7)) * 16) + (d & 7) * 2;
        *reinterpret_cast<short*>(Pw + byte) = f2bf(oac[m][nd][r]);
      }
#pragma unroll
  for (int it = 0; it < 4; ++it) {
    const int slot = it * 64 + lane;          // 0..255 -> 32q x 4 slots
    const int q = slot >> 3, sl = slot & 7;
    const int d0 = (sl ^ (q & 7)) * 8;
    s16x8 v = *reinterpret_cast<const s16x8*>(Pw + slot * 16);
    *reinterpret_cast<s16x8*>(
        &Og[rowbase + (size_t)(q0 + q) * 768 + d0]) = v;
  }
}

// ---------------------------------------------------------------------------
// Temporal attention (causal over S=16): per (b,p) block, 192 threads.
// K,V staged in LDS (48 KB, coalesced, h-interleaved layout). thread =
// (i = tid/12, h = tid%12). j-loop runs entirely from LDS.
// ---------------------------------------------------------------------------
__global__ __launch_bounds__(192)
void temporal_attn_kernel(const short* __restrict__ Qg, const short* __restrict__ Kg,
                          const short* __restrict__ Vg, short* __restrict__ Og)
{
  const int bp = blockIdx.x;
  const int b = bp >> 8, p = bp & 255;

  __shared__ short Ks[16 * 768];   // 24 KB
  __shared__ short Vs[16 * 768];   // 24 KB

  const int tid = threadIdx.x;
  const size_t gbase = ((size_t)(b * 16) * 256 + p) * 768;
  constexpr int SROW = 256 * 768;  // global row stride (s dimension)

  {
    const int half = tid / 96;           // 0..1
    const int cc   = tid - half * 96;    // 0..95
    const int c    = cc & 7, hs = cc >> 3;
    const int ldso = (c * 12 + hs) * 8;  // shorts within a row
#pragma unroll
    for (int it = 0; it < 8; ++it) {
      const int s = it * 2 + half;
      const size_t ga = gbase + (size_t)s * SROW + cc * 8;
      *reinterpret_cast<s16x8*>(&Ks[s * 768 + ldso]) =
          *reinterpret_cast<const s16x8*>(&Kg[ga]);
      *reinterpret_cast<s16x8*>(&Vs[s * 768 + ldso]) =
          *reinterpret_cast<const s16x8*>(&Vg[ga]);
    }
  }
  __syncthreads();

  const int h = tid % 12, i = tid / 12;
  const float scale = 0.125f;
  const size_t qoff = gbase + (size_t)i * SROW + h * 64;

  float q[HDc];
#pragma unroll
  for (int c = 0; c < 8; ++c) {
    s16x8 v = *reinterpret_cast<const s16x8*>(&Qg[qoff + c * 8]);
#pragma unroll
    for (int e = 0; e < 8; ++e) q[c * 8 + e] = bf2f(v[e]) * scale;
  }

  float m = -INFINITY, l = 0.f;
  float o[HDc];
#pragma unroll
  for (int d = 0; d < HDc; ++d) o[d] = 0.f;

  for (int j = 0; j <= i; ++j) {
    const short* kr = &Ks[j * 768];
    float s = 0.f;
#pragma unroll
    for (int c = 0; c < 8; ++c) {
      s16x8 kv = *reinterpret_cast<const s16x8*>(kr + (c * 12 + h) * 8);
#pragma unroll
      for (int e = 0; e < 8; ++e) s += q[c * 8 + e] * bf2f(kv[e]);
    }
    float mn   = fmaxf(m, s);
    float corr = __expf(m - mn);
    float pw   = __expf(s - mn);
    l = l * corr + pw;
    const short* vr = &Vs[j * 768];
#pragma unroll
    for (int c = 0; c < 8; ++c) {
      s16x8 vv = *reinterpret_cast<const s16x8*>(vr + (c * 12 + h) * 8);
#pragma unroll
      for (int e = 0; e < 8; ++e)
        o[c * 8 + e] = fmaf(pw, bf2f(vv[e]), o[c * 8 + e] * corr);
    }
    m = mn;
  }
  const float inv = 1.f / l;
  short* op = &Og[qoff];
#pragma unroll
  for (int c = 0; c < 8; ++c) {
    s16x8 v;
#pragma unroll
    for (int e = 0; e < 8; ++e) v[e] = f2bf(o[c * 8 + e] * inv);
    *reinterpret_cast<s16x8*>(op + c * 8) = v;
  }
}

// ---------------------------------------------------------------------------
// LayerNorm over E=768 (bf16 input U): one wave per row, 4 rows per block.
// ---------------------------------------------------------------------------
template<bool OUTBF>
__global__ __launch_bounds__(256)
void layernorm_kernel(const short* __restrict__ U, const float* __restrict__ g,
                      const float* __restrict__ be, void* __restrict__ outv)
{
  const int tid  = threadIdx.x;
  const int lane = tid & 63, w = tid >> 6;
  const size_t row = (size_t)blockIdx.x * 4 + w;
  const short* u = U + row * Ec;

  float x[12];
#pragma unroll
  for (int c = 0; c < 3; ++c) {
    s16x4 v = *reinterpret_cast<const s16x4*>(&u[c * 256 + lane * 4]);
    x[c*4+0] = bf2f(v[0]); x[c*4+1] = bf2f(v[1]);
    x[c*4+2] = bf2f(v[2]); x[c*4+3] = bf2f(v[3]);
  }
  float s = 0.f;
#pragma unroll
  for (int k = 0; k < 12; ++k) s += x[k];
#pragma unroll
  for (int off = 32; off > 0; off >>= 1) s += __shfl_xor(s, off, 64);
  const float mean = s * (1.f / 768.f);

  float vs = 0.f;
#pragma unroll
  for (int k = 0; k < 12; ++k) { float d = x[k] - mean; vs += d * d; }
#pragma unroll
  for (int off = 32; off > 0; off >>= 1) vs += __shfl_xor(vs, off, 64);
  const float rs = rsqrtf(vs * (1.f / 768.f) + 1e-5f);

#pragma unroll
  for (int c = 0; c < 3; ++c) {
    int idx = c * 256 + lane * 4;
    float4 gv = *reinterpret_cast<const float4*>(&g[idx]);
    float4 bv = *reinterpret_cast<const float4*>(&be[idx]);
    float r0 = (x[c*4+0] - mean) * rs * gv.x + bv.x;
    float r1 = (x[c*4+1] - mean) * rs * gv.y + bv.y;
    float r2 = (x[c*4+2] - mean) * rs * gv.z + bv.z;
    float r3 = (x[c*4+3] - mean) * rs * gv.w + bv.w;
    if (OUTBF) {
      short* op = (short*)outv + row * Ec + idx;
      s16x4 v = { f2bf(r0), f2bf(r1), f2bf(r2), f2bf(r3) };
      *reinterpret_cast<s16x4*>(op) = v;
    } else {
      float* op = (float*)outv + row * Ec + idx;
      *reinterpret_cast<float4*>(op) = make_float4(r0, r1, r2, r3);
    }
  }
}

// ---------------------------------------------------------------------------
extern "C" void kernel_launch(void* const* d_in, const int* in_sizes, int n_in,
                              void* d_out, int out_size, void* d_ws, size_t ws_size,
                              hipStream_t stream)
{
  const float* x       = (const float*)d_in[0];
  const float* sa_wqkv = (const float*)d_in[1];
  const float* sa_bqkv = (const float*)d_in[2];
  const float* sa_wo   = (const float*)d_in[3];
  const float* sa_bo   = (const float*)d_in[4];
  const float* sa_g    = (const float*)d_in[5];
  const float* sa_b    = (const float*)d_in[6];
  const float* ta_wqkv = (const float*)d_in[7];
  const float* ta_bqkv = (const float*)d_in[8];
  const float* ta_wo   = (const float*)d_in[9];
  const float* ta_bo   = (const float*)d_in[10];
  const float* ta_g    = (const float*)d_in[11];
  const float* ta_b    = (const float*)d_in[12];
  const float* f_w1    = (const float*)d_in[13];
  const float* f_b1    = (const float*)d_in[14];
  const float* f_w2    = (const float*)d_in[15];
  const float* f_b2    = (const float*)d_in[16];
  const float* f_g     = (const float*)d_in[17];
  const float* f_b     = (const float*)d_in[18];

  float* out = (float*)d_out;

  // ws layout: Xb bf16 ME | QKVH bf16 4*ME | U bf16 ME | Wt bf16 WTOT
  constexpr size_t EE = (size_t)Ec * Ec;           // 589824
  constexpr size_t WTOT = 3*EE + EE + 3*EE + EE + 2*(size_t)Ec*FFc;  // 9,437,184
  const size_t need = 12 * ME + 2 * WTOT;
  if (ws_size < need) return;   // clean absmax failure signals ws shortage

  short* Xb  = (short*)d_ws;
  short* Qb  = Xb + ME;
  short* Kb  = Qb + ME;
  short* Vtb = Qb + 2 * ME;     // spatial: transposed-V; temporal: normal V
  short* Hb  = Qb;              // FFN hidden reuses [1ME,5ME)
  short* U   = Xb + 5 * ME;
  short* Wtb = U + ME;

  short* wt_sa_qkv = Wtb;
  short* wt_sa_wo  = wt_sa_qkv + 3 * EE;
  short* wt_ta_qkv = wt_sa_wo  + EE;
  short* wt_ta_wo  = wt_ta_qkv + 3 * EE;
  short* wt_f_w1   = wt_ta_wo  + EE;
  short* wt_f_w2   = wt_f_w1   + (size_t)Ec * FFc;

  // ---- unified prep (weights transpose-convert + x->bf16), one dispatch ----
  prep_kernel<<<8448, 256, 0, stream>>>(
      x, Xb, sa_wqkv, wt_sa_qkv, sa_wo, wt_sa_wo,
      ta_wqkv, wt_ta_qkv, ta_wo, wt_ta_wo, f_w1, wt_f_w1, f_w2, wt_f_w2);

  // grids: BMT=2 -> (M/256)*(N/256); BMT=1 -> (M/128)*(N/256)
  const dim3 gQKV((Mrows / 256) * (Ec / 256), 1, 3);      // 192 x3
  const dim3 gSQ ((Mrows / 128) * (Ec / 256), 1, 1);      // 384 (BMT=1)
  const dim3 gFF1((Mrows / 256) * (FFc / 256), 1, 1);     // 768

  // ---- Stage A: spatial attention ----
  gemm256_kernel<4, 2><<<gQKV, 512, 0, stream>>>(Xb, wt_sa_qkv, sa_bqkv, nullptr, Qb, Vtb, Mrows, Ec, Ec);
  spatial_attn_kernel<<<dim3(Bc * Sc, Hc, 2), 256, 0, stream>>>(Qb, Kb, Vtb, Qb);
  gemm256_kernel<3, 1><<<gSQ, 512, 0, stream>>>(Qb, wt_sa_wo, sa_bo, Xb, U, nullptr, Mrows, Ec, Ec);
  layernorm_kernel<true><<<Mrows / 4, 256, 0, stream>>>(U, sa_g, sa_b, Xb);

  // ---- Stage B: temporal attention ----
  gemm256_kernel<0, 2><<<gQKV, 512, 0, stream>>>(Xb, wt_ta_qkv, ta_bqkv, nullptr, Qb, nullptr, Mrows, Ec, Ec);
  temporal_attn_kernel<<<Bc * Pc, 192, 0, stream>>>(Qb, Kb, Vtb, Qb);
  gemm256_kernel<3, 1><<<gSQ, 512, 0, stream>>>(Qb, wt_ta_wo, ta_bo, Xb, U, nullptr, Mrows, Ec, Ec);
  layernorm_kernel<true><<<Mrows / 4, 256, 0, stream>>>(U, ta_g, ta_b, Xb);

  // ---- Stage C: FFN ----
  gemm256_kernel<1, 2><<<gFF1, 512, 0, stream>>>(Xb, wt_f_w1, f_b1, nullptr, Hb, nullptr, Mrows, FFc, Ec);
  gemm256_kernel<3, 1><<<gSQ, 512, 0, stream>>>(Hb, wt_f_w2, f_b2, Xb, U, nullptr, Mrows, Ec, FFc);
  layernorm_kernel<false><<<Mrows / 4, 256, 0, stream>>>(U, f_g, f_b, out);
}